// Round 5
// baseline (1779.153 us; speedup 1.0000x reference)
//
#include <hip/hip_runtime.h>
#include <hip/hip_bf16.h>

#define MINF 1e-15f
#define EPSF 1e-6f

// ---------- workspace layout (floats) ----------
#define OFF_P    0u            // 16*2000*100      = 3,200,000
#define OFF_UX   3200000u      // 2*3*32000*100    = 19,200,000
#define OFF_WT4  22400000u     // 2*3*25*100*4     = 60,000
#define OFF_F    22460000u     // 16*20*100*200    = 6,400,000
#define OFF_CL   28860000u     // 201 (pad 256)
#define OFF_A    28860256u     // 32000
#define OFF_G    28892256u     // 32000
#define OFF_WGT  28924256u     // 32000
// Region reuse (all stream-ordered, re-packed every call):
//   wi4/w1p live in the f region until k3 overwrites f.
//   mx (raw Wp-GEMM output) reuses the ux region (dead after k3).
//   wp4 reuses the aa/gg region (dead until k4ae writes aa/gg).
//   nub (k2b: |ux|^2 [0,192000) and <ux,b> [192000,384000)) reuses the p
//   region (dead after k2; k2b runs between k2 and k3).
#define OFF_WI4  OFF_F
#define OFF_W1P  (OFF_F + 60000u)
#define OFF_MX   OFF_UX
#define OFF_WP4  OFF_A
#define OFF_NUB  OFF_P

#define K3_LDS_BYTES 155840    // (30000 + 16*3*112 + 16*112 + 16*112) * 4
#define K2_LDS_BYTES ((3200 + 64*26)*16 + 64*4)   // W 51200 + p 26624 + alx 256 = 78080
#define K4G_LDS_BYTES ((3200 + 64*26)*16)         // W 51200 + f 26624 = 77824

__device__ __forceinline__ float wred(float v) {
#pragma unroll
  for (int m = 32; m > 0; m >>= 1) v += __shfl_xor(v, m, 64);
  return v;
}
__device__ __forceinline__ float wredmax(float v) {
#pragma unroll
  for (int m = 32; m > 0; m >>= 1) v = fmaxf(v, __shfl_xor(v, m, 64));
  return v;
}
__device__ __forceinline__ float artanh_c(float x) {
  x = fminf(x, 1.f - 1e-7f);
  return 0.5f * (log1pf(x) - log1pf(-x));
}
__device__ __forceinline__ float arcosh_(float x) {
  return logf(x) + log1pf(sqrtf(fmaxf(x * x - 1.f + EPSF, 0.f)) / x);
}
__device__ __forceinline__ float sigm(float x) { return 1.f / (1.f + expf(-x)); }

// ---------------- K0a: pack weights into float4-friendly layouts ----------------
__global__ void k0_pack(const float* __restrict__ whh_f, const float* __restrict__ whh_b,
                        const float* __restrict__ wih_f, const float* __restrict__ wih_b,
                        const float* __restrict__ W1, const float* __restrict__ Wp,
                        float* __restrict__ wt4, float* __restrict__ wi4,
                        float* __restrict__ w1p, float* __restrict__ wp4) {
  int idx = blockIdx.x * 256 + threadIdx.x;
  if (idx < 60000) {
    int kk = idx & 3; int t = idx >> 2;
    int j = t % 100; t /= 100;
    int k4 = t % 25; t /= 25;
    int g = t % 3; int dir = t / 3;
    const float* src = dir ? whh_b : whh_f;
    wt4[idx] = src[g * 10000 + j * 100 + k4 * 4 + kk];
  } else if (idx < 120000) {
    int i2 = idx - 60000;
    int kk = i2 & 3; int t = i2 >> 2;
    int c = t % 100; t /= 100;
    int k4 = t % 25; t /= 25;
    int g = t % 3; int dir = t / 3;
    const float* src = dir ? wih_b : wih_f;
    wi4[i2] = src[g * 10000 + c * 100 + k4 * 4 + kk];
  } else if (idx < 196800) {
    int i2 = idx - 120000;
    int kk = i2 & 3; int t = i2 >> 2;
    int c = t % 100; int k4 = t / 100;
    w1p[i2] = W1[c * 768 + k4 * 4 + kk];
  } else if (idx < 236800) {
    int i3 = idx - 196800;
    int kk = i3 & 3; int t = i3 >> 2;
    int c = t % 100; int t2 = t / 100;
    int k4 = t2 % 50; int ch = t2 / 50;
    wp4[i3] = Wp[(size_t)(ch * 100 + c) * 200 + k4 * 4 + kk];
  }
}

// ---------------- K0b: lorentz_activation(centroid) -> cl[201] ----------------
__global__ void k0_cl(const float* __restrict__ centroid, float* __restrict__ cl) {
  __shared__ float sred[4];
  int t = threadIdx.x;
  float v = (t < 200) ? centroid[t] : 0.f;
  float ps = wred(v * v);
  if ((t & 63) == 0) sred[t >> 6] = ps;
  __syncthreads();
  float r = sqrtf(sred[0] + sred[1] + sred[2] + sred[3]);
  if (t < 200) cl[t] = v / r * sinhf(r);
  if (t == 0) cl[200] = coshf(r);
}

// ---------------- K1: klein(x_) @ W1^T + b1, poincare project -> p ----------------
__global__ __launch_bounds__(256, 2) void k1(const float* __restrict__ x_,
                                             const float* __restrict__ w1p,
                                             const float* __restrict__ b1,
                                             float* __restrict__ p) {
  __shared__ float4 wl[16 * 128];
  __shared__ float4 xl[64 * 16];
  __shared__ float ns[64];
  __shared__ float sscale[64];
  int t = threadIdx.x;
  int row0 = blockIdx.x * 64;
  int cg = t & 31, rg = t >> 5;
  const float4* wsrc = (const float4*)w1p;
  float nacc[4] = {0, 0, 0, 0};
  float acc[8][4] = {};
  for (int kc = 0; kc < 12; kc++) {
    int k0f4 = kc * 16;
    __syncthreads();
#pragma unroll
    for (int q = 0; q < 4; q++) {
      int idx = t + 256 * q;
      int r = idx >> 4, c4 = idx & 15;
      float4 v = *(const float4*)(x_ + (size_t)(row0 + r) * 768 + (size_t)(k0f4 + c4) * 4);
      xl[idx] = v;
      nacc[q] += v.x * v.x + v.y * v.y + v.z * v.z + v.w * v.w;
    }
#pragma unroll
    for (int q = 0; q < 8; q++) {
      int idx = t + 256 * q;
      int k4 = idx >> 7, c = idx & 127;
      float4 v = {0, 0, 0, 0};
      if (c < 100) v = wsrc[(size_t)(k0f4 + k4) * 100 + c];
      wl[idx] = v;
    }
    __syncthreads();
#pragma unroll 4
    for (int k4 = 0; k4 < 16; k4++) {
      float4 wv[4];
#pragma unroll
      for (int j = 0; j < 4; j++) wv[j] = wl[k4 * 128 + cg + 32 * j];
#pragma unroll
      for (int i = 0; i < 8; i++) {
        float4 pv = xl[(rg * 8 + i) * 16 + k4];
#pragma unroll
        for (int j = 0; j < 4; j++)
          acc[i][j] += pv.x * wv[j].x + pv.y * wv[j].y + pv.z * wv[j].z + pv.w * wv[j].w;
      }
    }
  }
  __syncthreads();
#pragma unroll
  for (int q = 0; q < 4; q++) {
    float v = nacc[q];
#pragma unroll
    for (int m = 8; m > 0; m >>= 1) v += __shfl_xor(v, m, 64);
    if ((t & 15) == 0) ns[(t >> 4) + 16 * q] = v;
  }
  __syncthreads();
  if (t < 64) {
    float rr = sqrtf(fmaxf(ns[t], MINF));
    sscale[t] = tanhf(rr) / rr;
  }
  __syncthreads();
  float bcol[4];
#pragma unroll
  for (int j = 0; j < 4; j++) {
    int col = cg + 32 * j;
    bcol[j] = (col < 100) ? b1[col] : 0.f;
  }
#pragma unroll
  for (int i = 0; i < 8; i++) {
    int r = rg * 8 + i;
    float s = sscale[r];
    float hv[4]; float ss = 0.f;
#pragma unroll
    for (int j = 0; j < 4; j++) {
      int col = cg + 32 * j;
      hv[j] = (col < 100) ? (s * acc[i][j] + bcol[j]) : 0.f;
      ss += hv[j] * hv[j];
    }
#pragma unroll
    for (int m = 16; m > 0; m >>= 1) ss += __shfl_xor(ss, m, 64);
    float inv = 1.f / sqrtf(1.f + ss);
    float* prow = p + (size_t)(row0 + r) * 100;
#pragma unroll
    for (int j = 0; j < 4; j++) {
      int col = cg + 32 * j;
      if (col < 100) prow[col] = hv[j] * inv;
    }
  }
}

// ---------------- K2: ux[combo][row] = m_matvec(Wih_combo, p[row]) ----------------
__global__ __launch_bounds__(256, 2) void k2(const float* __restrict__ p,
                                             const float* __restrict__ wi4,
                                             float* __restrict__ ux) {
  extern __shared__ float4 l4[];
  float4* wl = l4;
  float4* pl = l4 + 3200;
  float* alx = (float*)(l4 + 3200 + 64 * 26);
  int t = threadIdx.x;
  int bx = blockIdx.x;
  int combo = bx / 500, tile = bx % 500;
  int row0 = tile * 64;
  int cg = t & 31, rg = t >> 5;
  const float4* wsrc = (const float4*)wi4 + (size_t)combo * 2500;
#pragma unroll
  for (int q = 0; q < 13; q++) {
    int idx = t + 256 * q;
    if (idx < 3200) {
      int k4 = idx >> 7, c = idx & 127;
      float4 v = {0, 0, 0, 0};
      if (c < 100) v = wsrc[k4 * 100 + c];
      wl[idx] = v;
    }
  }
  const float4* psrc = (const float4*)(p + (size_t)row0 * 100);
#pragma unroll
  for (int q = 0; q < 7; q++) {
    int idx = t + 256 * q;
    if (idx < 1600) {
      int r = idx / 25, c4 = idx % 25;
      pl[r * 26 + c4] = psrc[idx];
    }
  }
  __syncthreads();
  {
    int w = t >> 6, lane = t & 63;
    const float* pf = (const float*)pl;
    for (int r = w * 16; r < w * 16 + 16; r++) {
      float v0 = pf[r * 104 + lane];
      float v1 = (lane < 36) ? pf[r * 104 + 64 + lane] : 0.f;
      float s2 = wred(v0 * v0 + v1 * v1);
      if (lane == 0) {
        float xn = sqrtf(fmaxf(s2, MINF));
        alx[r] = artanh_c(xn) / xn;
      }
    }
  }
  __syncthreads();
  float acc[8][4] = {};
#pragma unroll 5
  for (int k4 = 0; k4 < 25; k4++) {
    float4 wv[4];
#pragma unroll
    for (int j = 0; j < 4; j++) wv[j] = wl[k4 * 128 + cg + 32 * j];
#pragma unroll
    for (int i = 0; i < 8; i++) {
      float4 pv = pl[(rg * 8 + i) * 26 + k4];
#pragma unroll
      for (int j = 0; j < 4; j++)
        acc[i][j] += pv.x * wv[j].x + pv.y * wv[j].y + pv.z * wv[j].z + pv.w * wv[j].w;
    }
  }
#pragma unroll
  for (int i = 0; i < 8; i++) {
    int r = rg * 8 + i;
    float ss = acc[i][0] * acc[i][0] + acc[i][1] * acc[i][1] +
               acc[i][2] * acc[i][2] + acc[i][3] * acc[i][3];
#pragma unroll
    for (int m = 16; m > 0; m >>= 1) ss += __shfl_xor(ss, m, 64);
    float mxn = sqrtf(fmaxf(ss, MINF));
    float sc = tanhf(mxn * alx[r]) / mxn;
    float* dst = ux + ((size_t)combo * 32000 + row0 + r) * 100;
#pragma unroll
    for (int j = 0; j < 4; j++) {
      int col = cg + 32 * j;
      if (col < 100) dst[col] = sc * acc[i][j];
    }
  }
}

// ---------------- K2b: per-(combo,row) |ux|^2 and <ux,bias_g> ----------------
// grid 3000 (64 rows each, never straddles a combo: 32000%64==0), block 256.
__global__ __launch_bounds__(256) void k2b(const float* __restrict__ ux,
                                           const float* __restrict__ bias_f,
                                           const float* __restrict__ bias_b,
                                           float* __restrict__ nub) {
  int t = threadIdx.x; int w = t >> 6; int lane = t & 63;
  int gr0 = blockIdx.x * 64;
  int combo = gr0 / 32000;
  int dir = combo / 3, g = combo % 3;
  const float* bias = (dir ? bias_b : bias_f) + g * 100;
  float b0 = bias[lane];
  float b1 = (lane < 36) ? bias[64 + lane] : 0.f;
  for (int i = w * 16; i < w * 16 + 16; i++) {
    const float* u = ux + (size_t)(gr0 + i) * 100;
    float u0 = u[lane];
    float u1 = (lane < 36) ? u[64 + lane] : 0.f;
    float n2 = wred(u0 * u0 + u1 * u1);
    float ub = wred(u0 * b0 + u1 * b1);
    if (lane == 0) { nub[gr0 + i] = n2; nub[192000 + gr0 + i] = ub; }
  }
}

// ---------------- K3: sequential Mobius GRU ----------------
// onetrans via scalar identities: with A=|m|^2, B=<m,ux>, C=|ux|^2 (precomp),
// Mb=<m,b>, ub=<ux,b> (precomp): a = cA*m+cB*ux gives D=|a|^2, E=<a,b>, and
// F=|c|^2 all scalar — 3 wreds instead of 5, and downstream |c|^2 norms free.
__device__ __forceinline__ void gate_ot(float m0, float m1, float u0, float u1,
                                        float b0v, float b1v, float C, float ub, float nb2,
                                        float alphah,
                                        float& c0, float& c1, float& Fout) {
  float A = wred(m0 * m0 + m1 * m1);
  float B = wred(m0 * u0 + m1 * u1);
  float Mb = wred(m0 * b0v + m1 * b1v);
  float mxn = sqrtf(fmaxf(A, MINF));
  float gam = tanhf(mxn * alphah) / mxn;
  float x2 = gam * gam * A, xy = gam * B;
  float rd = 1.f / fmaxf(1.f + 2.f * xy + x2 * C, MINF);
  float cA = (1.f + 2.f * xy + C) * gam * rd, cB = (1.f - x2) * rd;
  float D = fmaxf(cA * cA * A + 2.f * cA * cB * B + cB * cB * C, 0.f);
  float E = cA * Mb + cB * ub;
  float r2 = 1.f / fmaxf(1.f + 2.f * E + D * nb2, MINF);
  float t1 = (1.f + 2.f * E + nb2) * r2, t2 = (1.f - D) * r2;
  c0 = t1 * (cA * m0 + cB * u0) + t2 * b0v;
  c1 = t1 * (cA * m1 + cB * u1) + t2 * b1v;
  Fout = fmaxf(t1 * t1 * D + 2.f * t1 * t2 * E + t2 * t2 * nb2, MINF);
}

// grid 256 (32 groups x 8 row-chunks), block 1024, dyn LDS 155840 B.
// Matvecs W-amortized: waves 12..15 each carry 4 rows in scalar accumulators,
// reading each W float4 once per 4 rows (LDS reads/step: M1 1625->800, M2 975->600).
__global__ __launch_bounds__(1024, 4) void k3(const float* __restrict__ ux,
                                              const float* __restrict__ nub,
                                              const float* __restrict__ wt4,
                                              const float* __restrict__ bias_f,
                                              const float* __restrict__ bias_b,
                                              float* __restrict__ f) {
  extern __shared__ float lds[];
  float* Wlds = lds;                 // 30000
  float* mvl = lds + 30000;          // 16*3*112 = 5376
  float* hl = mvl + 16 * 3 * 112;    // 16*112 = 1792
  float* rhl = hl + 16 * 112;        // 16*112 = 1792
  int t = threadIdx.x; int w = t >> 6; int lane = t & 63;
  bool hi = lane < 36;
  int bx = blockIdx.x;
  int grp = bx >> 3; int blki = bx & 7;
  int n = grp >> 1; int dir = grp & 1;
  int b0 = blki * 13; int nrows = min(13, 100 - b0);
  const float* bias = dir ? bias_b : bias_f;
  const float* wsrc = wt4 + dir * 30000;
#pragma unroll
  for (int q = 0; q < 30; q++) { int idx = t + 1024 * q; if (idx < 30000) Wlds[idx] = wsrc[idx]; }
#pragma unroll
  for (int q = 0; q < 4; q++) { int idx = t + 1024 * q; if (idx < 2 * 16 * 112) hl[idx] = 0.f; }
  __syncthreads();

  int row = w; bool erow = (w < nrows);
  int b = b0 + row;
  float nh2 = 0.f, h0 = 0.f, h1 = 0.f;
  float bz0 = 0, bz1 = 0, br0 = 0, br1 = 0, bh0 = 0, bh1 = 0, nbz2 = 0, nbr2 = 0, nbh2 = 0;
  if (erow) {
    br0 = bias[lane];        if (hi) br1 = bias[64 + lane];
    bh0 = bias[100 + lane];  if (hi) bh1 = bias[164 + lane];
    bz0 = bias[200 + lane];  if (hi) bz1 = bias[264 + lane];
    nbr2 = wred(br0 * br0 + br1 * br1);
    nbh2 = wred(bh0 * bh0 + bh1 * bh1);
    nbz2 = wred(bz0 * bz0 + bz1 * bz1);
  }
  for (int s = 0; s < 20; s++) {
    float uz0 = 0, uz1 = 0, ur0 = 0, ur1 = 0, uxh0 = 0, uxh1 = 0;
    float Cz = 0, Cr = 0, Ch = 0, ubz = 0, ubr = 0, ubh = 0;
    if (erow) {
      // issue global loads early — they complete under the M1 GEMM
      int l = dir ? (1999 - (s * 100 + b)) : (s * 100 + b);
      size_t rowg = (size_t)n * 2000 + l;
      size_t iz = (size_t)(dir * 3 + 2) * 32000 + rowg;
      size_t ir = (size_t)(dir * 3 + 0) * 32000 + rowg;
      size_t ih = (size_t)(dir * 3 + 1) * 32000 + rowg;
      const float* uxz = ux + iz * 100;
      const float* uxr = ux + ir * 100;
      const float* uxhp = ux + ih * 100;
      uz0 = uxz[lane];  uz1 = hi ? uxz[lane + 64] : 0.f;
      ur0 = uxr[lane];  ur1 = hi ? uxr[lane + 64] : 0.f;
      uxh0 = uxhp[lane]; uxh1 = hi ? uxhp[lane + 64] : 0.f;
      Cz = nub[iz]; ubz = nub[192000 + iz];
      Cr = nub[ir]; ubr = nub[192000 + ir];
      Ch = nub[ih]; ubh = nub[192000 + ih];
    }
    // ---- M1: z(g=2)+r(g=0) GEMM, 4 waves x 4 rows ----
    if (w >= 12) {
      int r0g = (w - 12) * 4;
      const float4* Wz4 = (const float4*)(Wlds + 2 * 10000);
      const float4* Wr4 = (const float4*)(Wlds + 0 * 10000);
      float az0[4] = {}, az1[4] = {}, ar0a[4] = {}, ar1a[4] = {};
#pragma unroll 5
      for (int k4 = 0; k4 < 25; k4++) {
        float4 hv0 = *(const float4*)(hl + (r0g + 0) * 112 + k4 * 4);
        float4 hv1 = *(const float4*)(hl + (r0g + 1) * 112 + k4 * 4);
        float4 hv2 = *(const float4*)(hl + (r0g + 2) * 112 + k4 * 4);
        float4 hv3 = *(const float4*)(hl + (r0g + 3) * 112 + k4 * 4);
        float4 wz = Wz4[k4 * 100 + lane];
        float4 wr = Wr4[k4 * 100 + lane];
        az0[0] += wz.x * hv0.x + wz.y * hv0.y + wz.z * hv0.z + wz.w * hv0.w;
        az0[1] += wz.x * hv1.x + wz.y * hv1.y + wz.z * hv1.z + wz.w * hv1.w;
        az0[2] += wz.x * hv2.x + wz.y * hv2.y + wz.z * hv2.z + wz.w * hv2.w;
        az0[3] += wz.x * hv3.x + wz.y * hv3.y + wz.z * hv3.z + wz.w * hv3.w;
        ar0a[0] += wr.x * hv0.x + wr.y * hv0.y + wr.z * hv0.z + wr.w * hv0.w;
        ar0a[1] += wr.x * hv1.x + wr.y * hv1.y + wr.z * hv1.z + wr.w * hv1.w;
        ar0a[2] += wr.x * hv2.x + wr.y * hv2.y + wr.z * hv2.z + wr.w * hv2.w;
        ar0a[3] += wr.x * hv3.x + wr.y * hv3.y + wr.z * hv3.z + wr.w * hv3.w;
        if (hi) {
          float4 wzh = Wz4[k4 * 100 + 64 + lane];
          float4 wrh = Wr4[k4 * 100 + 64 + lane];
          az1[0] += wzh.x * hv0.x + wzh.y * hv0.y + wzh.z * hv0.z + wzh.w * hv0.w;
          az1[1] += wzh.x * hv1.x + wzh.y * hv1.y + wzh.z * hv1.z + wzh.w * hv1.w;
          az1[2] += wzh.x * hv2.x + wzh.y * hv2.y + wzh.z * hv2.z + wzh.w * hv2.w;
          az1[3] += wzh.x * hv3.x + wzh.y * hv3.y + wzh.z * hv3.z + wzh.w * hv3.w;
          ar1a[0] += wrh.x * hv0.x + wrh.y * hv0.y + wrh.z * hv0.z + wrh.w * hv0.w;
          ar1a[1] += wrh.x * hv1.x + wrh.y * hv1.y + wrh.z * hv1.z + wrh.w * hv1.w;
          ar1a[2] += wrh.x * hv2.x + wrh.y * hv2.y + wrh.z * hv2.z + wrh.w * hv2.w;
          ar1a[3] += wrh.x * hv3.x + wrh.y * hv3.y + wrh.z * hv3.z + wrh.w * hv3.w;
        }
      }
#pragma unroll
      for (int i = 0; i < 4; i++) {
        float* oz = mvl + ((r0g + i) * 3 + 2) * 112;
        float* orr = mvl + ((r0g + i) * 3 + 0) * 112;
        oz[lane] = az0[i]; orr[lane] = ar0a[i];
        if (hi) { oz[64 + lane] = az1[i]; orr[64 + lane] = ar1a[i]; }
      }
    }
    __syncthreads();
    // ---- pt1: z, r gates + rh ----
    float z0 = 0, z1 = 0, nrh2 = 0, alphah = 0;
    if (erow) {
      float xnh = sqrtf(fmaxf(nh2, MINF));
      alphah = artanh_c(xnh) / xnh;
      const float* mzp = mvl + (row * 3 + 2) * 112;
      const float* mrp = mvl + (row * 3 + 0) * 112;
      float mz0 = mzp[lane], mz1 = hi ? mzp[64 + lane] : 0.f;
      float mr0 = mrp[lane], mr1 = hi ? mrp[64 + lane] : 0.f;
      float cz0, cz1, Fz, cr0, cr1, Fr;
      gate_ot(mz0, mz1, uz0, uz1, bz0, bz1, Cz, ubz, nbz2, alphah, cz0, cz1, Fz);
      gate_ot(mr0, mr1, ur0, ur1, br0, br1, Cr, ubr, nbr2, alphah, cr0, cr1, Fr);
      float cnz = sqrtf(Fz); float lgz = artanh_c(cnz) / cnz;
      z0 = sigm(lgz * cz0); z1 = sigm(lgz * cz1);
      float cnr = sqrtf(Fr); float lgr = artanh_c(cnr) / cnr;
      float rg0 = sigm(lgr * cr0), rg1 = sigm(lgr * cr1);
      float mx0 = rg0 * h0, mx1 = rg1 * h1;
      float G = wred(mx0 * mx0 + mx1 * mx1);
      float mxnr = sqrtf(fmaxf(G, MINF));
      float srh = tanhf(mxnr * alphah) / mxnr;
      rhl[row * 112 + lane] = srh * mx0;
      if (hi) rhl[row * 112 + lane + 64] = srh * mx1;
      nrh2 = srh * srh * G;
    }
    __syncthreads();
    // ---- M2: h-gate (g=1) GEMM on rhl, 4 waves x 4 rows ----
    if (w >= 12) {
      int r0g = (w - 12) * 4;
      const float4* Wh4 = (const float4*)(Wlds + 1 * 10000);
      float ah0[4] = {}, ah1[4] = {};
#pragma unroll 5
      for (int k4 = 0; k4 < 25; k4++) {
        float4 rv0 = *(const float4*)(rhl + (r0g + 0) * 112 + k4 * 4);
        float4 rv1 = *(const float4*)(rhl + (r0g + 1) * 112 + k4 * 4);
        float4 rv2 = *(const float4*)(rhl + (r0g + 2) * 112 + k4 * 4);
        float4 rv3 = *(const float4*)(rhl + (r0g + 3) * 112 + k4 * 4);
        float4 wh = Wh4[k4 * 100 + lane];
        ah0[0] += wh.x * rv0.x + wh.y * rv0.y + wh.z * rv0.z + wh.w * rv0.w;
        ah0[1] += wh.x * rv1.x + wh.y * rv1.y + wh.z * rv1.z + wh.w * rv1.w;
        ah0[2] += wh.x * rv2.x + wh.y * rv2.y + wh.z * rv2.z + wh.w * rv2.w;
        ah0[3] += wh.x * rv3.x + wh.y * rv3.y + wh.z * rv3.z + wh.w * rv3.w;
        if (hi) {
          float4 whh = Wh4[k4 * 100 + 64 + lane];
          ah1[0] += whh.x * rv0.x + whh.y * rv0.y + whh.z * rv0.z + whh.w * rv0.w;
          ah1[1] += whh.x * rv1.x + whh.y * rv1.y + whh.z * rv1.z + whh.w * rv1.w;
          ah1[2] += whh.x * rv2.x + whh.y * rv2.y + whh.z * rv2.z + whh.w * rv2.w;
          ah1[3] += whh.x * rv3.x + whh.y * rv3.y + whh.z * rv3.z + whh.w * rv3.w;
        }
      }
#pragma unroll
      for (int i = 0; i < 4; i++) {
        float* oh = mvl + ((r0g + i) * 3 + 1) * 112;
        oh[lane] = ah0[i];
        if (hi) oh[64 + lane] = ah1[i];
      }
    }
    __syncthreads();
    // ---- pt2: htil, d, pw, hn ----
    if (erow) {
      float xnrh = sqrtf(fmaxf(nrh2, MINF));
      float alpharh = artanh_c(xnrh) / xnrh;
      const float* mhp = mvl + (row * 3 + 1) * 112;
      float mh0 = mhp[lane], mh1 = hi ? mhp[64 + lane] : 0.f;
      float ct0, ct1, T;
      gate_ot(mh0, mh1, uxh0, uxh1, bh0, bh1, Ch, ubh, nbh2, alpharh, ct0, ct1, T);
      float U = wred(h0 * ct0 + h1 * ct1);
      float rdd = 1.f / fmaxf(1.f - 2.f * U + nh2 * T, MINF);
      float cAd = (1.f - 2.f * U + T) * rdd, cBd = (1.f - nh2) * rdd;
      float d0 = -cAd * h0 + cBd * ct0, d1 = -cAd * h1 + cBd * ct1;
      float nd2 = fmaxf(cAd * cAd * nh2 - 2.f * cAd * cBd * U + cBd * cBd * T, MINF);
      float zd0 = z0 * d0, zd1 = z1 * d1;
      float P = wred(zd0 * zd0 + zd1 * zd1);
      float Q = wred(h0 * zd0 + h1 * zd1);
      float xnd = sqrtf(nd2);
      float mxnp = sqrtf(fmaxf(P, MINF));
      float sp = tanhf(mxnp * artanh_c(xnd) / xnd) / mxnp;
      float y2p = sp * sp * P, xyp = sp * Q;
      float r3 = 1.f / fmaxf(1.f + 2.f * xyp + nh2 * y2p, MINF);
      float A1 = (1.f + 2.f * xyp + y2p) * r3, B1 = (1.f - nh2) * r3 * sp;
      float hn0 = A1 * h0 + B1 * zd0, hn1 = A1 * h1 + B1 * zd1;
      nh2 = fmaxf(A1 * A1 * nh2 + 2.f * A1 * B1 * Q + B1 * B1 * P, 0.f);
      h0 = hn0; h1 = hn1;
      hl[row * 112 + lane] = hn0;
      if (hi) hl[row * 112 + lane + 64] = hn1;
      float* fd = f + (((size_t)n * 20 + s) * 100 + b) * 200 + dir * 100;
      fd[lane] = hn0;
      if (hi) fd[lane + 64] = hn1;
    }
    __syncthreads();
  }
}

// ---------------- K4ag: mx = f @ Wp^T (raw), register-tiled ----------------
__global__ __launch_bounds__(256, 2) void k4ag(const float* __restrict__ f,
                                               const float* __restrict__ wp4,
                                               float* __restrict__ mx) {
  extern __shared__ float4 g4[];
  float4* wl = g4;
  float4* pl = g4 + 3200;
  int t = threadIdx.x;
  int bx = blockIdx.x;
  int ch = bx & 1, tile = bx >> 1;
  int row0 = tile * 64;
  int cg = t & 31, rg = t >> 5;
  const float4* wsrc = (const float4*)wp4 + (size_t)ch * 5000;
  const float4* psrc = (const float4*)(f + (size_t)row0 * 200);
  float acc[8][4] = {};
  for (int kc = 0; kc < 2; kc++) {
    __syncthreads();
#pragma unroll
    for (int q = 0; q < 13; q++) {
      int idx = t + 256 * q;
      if (idx < 3200) {
        int k4 = idx >> 7, c = idx & 127;
        float4 v = {0, 0, 0, 0};
        if (c < 100) v = wsrc[(kc * 25 + k4) * 100 + c];
        wl[idx] = v;
      }
    }
#pragma unroll
    for (int q = 0; q < 7; q++) {
      int idx = t + 256 * q;
      if (idx < 1600) {
        int r = idx / 25, k4 = idx % 25;
        pl[r * 26 + k4] = psrc[r * 50 + kc * 25 + k4];
      }
    }
    __syncthreads();
#pragma unroll 5
    for (int k4 = 0; k4 < 25; k4++) {
      float4 wv[4];
#pragma unroll
      for (int j = 0; j < 4; j++) wv[j] = wl[k4 * 128 + cg + 32 * j];
#pragma unroll
      for (int i = 0; i < 8; i++) {
        float4 pv = pl[(rg * 8 + i) * 26 + k4];
#pragma unroll
        for (int j = 0; j < 4; j++)
          acc[i][j] += pv.x * wv[j].x + pv.y * wv[j].y + pv.z * wv[j].z + pv.w * wv[j].w;
      }
    }
  }
#pragma unroll
  for (int i = 0; i < 8; i++) {
    float* dst = mx + (size_t)(row0 + rg * 8 + i) * 200 + ch * 100;
#pragma unroll
    for (int j = 0; j < 4; j++) {
      int col = cg + 32 * j;
      if (col < 100) dst[col] = acc[i][j];
    }
  }
}

// ---------------- K4ae: Mobius m_add(bp) + lorentz logits a, gamma ----------------
__global__ __launch_bounds__(256) void k4ae(const float* __restrict__ f,
                                            const float* __restrict__ mx,
                                            const float* __restrict__ bp,
                                            const float* __restrict__ cl,
                                            const float* __restrict__ beta_p,
                                            float* __restrict__ a_out, float* __restrict__ g_out) {
  int t = threadIdx.x; int w = t >> 6; int lane = t & 63;
  int row0 = blockIdx.x * 64;
  float beta = beta_p[0];
  float c200 = cl[200];
  float b_0 = bp[lane], b_1 = bp[lane + 64], b_2 = bp[lane + 128];
  float b_3 = (lane < 8) ? bp[lane + 192] : 0.f;
  float c_0 = cl[lane], c_1 = cl[lane + 64], c_2 = cl[lane + 128];
  float c_3 = (lane < 8) ? cl[lane + 192] : 0.f;
  float nbp2 = wred(b_0 * b_0 + b_1 * b_1 + b_2 * b_2 + b_3 * b_3);
  for (int r = w * 16; r < w * 16 + 16; r++) {
    const float* fr = f + (size_t)(row0 + r) * 200;
    const float* mr = mx + (size_t)(row0 + r) * 200;
    float f0 = fr[lane], f1 = fr[lane + 64], f2 = fr[lane + 128];
    float f3 = (lane < 8) ? fr[lane + 192] : 0.f;
    float nf2 = wred(f0 * f0 + f1 * f1 + f2 * f2 + f3 * f3);
    float xn = sqrtf(fmaxf(nf2, MINF));
    float alx = artanh_c(xn) / xn;
    float m0 = mr[lane], m1 = mr[lane + 64], m2 = mr[lane + 128];
    float m3 = (lane < 8) ? mr[lane + 192] : 0.f;
    float A = wred(m0 * m0 + m1 * m1 + m2 * m2 + m3 * m3);
    float B = wred(m0 * b_0 + m1 * b_1 + m2 * b_2 + m3 * b_3);
    float mxn = sqrtf(fmaxf(A, MINF));
    float gam = tanhf(mxn * alx) / mxn;
    float x2 = gam * gam * A, y2 = nbp2, xy = gam * B;
    float rd = 1.f / fmaxf(1.f + 2.f * xy + x2 * y2, MINF);
    float cA = (1.f + 2.f * xy + y2) * gam * rd, cB = (1.f - x2) * rd;
    float a0 = cA * m0 + cB * b_0, a1 = cA * m1 + cB * b_1;
    float a2 = cA * m2 + cB * b_2, a3 = cA * m3 + cB * b_3;
    float r2 = wred(a0 * a0 + a1 * a1 + a2 * a2 + a3 * a3);
    float dc = wred(a0 * c_0 + a1 * c_1 + a2 * c_2 + a3 * c_3);
    float pm = (-2.f * dc + (1.f + r2) * c200) / (1.f - r2 + EPSF);
    pm = fminf(fmaxf(pm, 1.f + EPSF), 1e16f);
    float av = -beta * arcosh_(pm) - 1.f;
    float invg = 1.f - 4.f * nf2 / ((1.f + nf2) * (1.f + nf2));
    invg = fminf(fmaxf(invg, EPSF), 1.f - EPSF);
    float gv = fminf(fmaxf(1.f / sqrtf(invg), 1.f + EPSF), 1e16f);
    if (lane == 0) { a_out[row0 + r] = av; g_out[row0 + r] = gv; }
  }
}

// ---------------- K4b: per-sample softmax weights ----------------
__global__ __launch_bounds__(256) void k4b(const float* __restrict__ a_in,
                                           const float* __restrict__ g_in,
                                           float* __restrict__ wgt) {
  __shared__ float rl[2000];
  __shared__ float sred[4];
  __shared__ float rsinv[100];
  int n = blockIdx.x; int t = threadIdx.x;
  int w = t >> 6, lane = t & 63;
  const float* ap = a_in + n * 2000;
  const float* gp = g_in + n * 2000;
  float av[8]; float am = -1e30f;
#pragma unroll
  for (int q = 0; q < 8; q++) {
    int i = t + 256 * q;
    av[q] = (i < 2000) ? ap[i] : -1e30f;
    am = fmaxf(am, av[q]);
  }
  am = wredmax(am);
  if (lane == 0) sred[w] = am;
  __syncthreads();
  float amax = fmaxf(fmaxf(sred[0], sred[1]), fmaxf(sred[2], sred[3]));
#pragma unroll
  for (int q = 0; q < 8; q++) {
    int i = t + 256 * q;
    if (i < 2000) rl[i] = expf(av[q] - amax) * gp[i];
  }
  __syncthreads();
  if (t < 100) {
    float ssum = 0.f;
#pragma unroll
    for (int s = 0; s < 20; s++) ssum += rl[s * 100 + t];
    rsinv[t] = 1.f / ssum;
  }
  __syncthreads();
#pragma unroll
  for (int q = 0; q < 8; q++) {
    int i = t + 256 * q;
    if (i < 2000) wgt[n * 2000 + i] = rl[i] * rsinv[i % 100];
  }
}

// ---------------- K4c: klein aggregation + final GEMM W2 ----------------
__global__ __launch_bounds__(256) void k4c(const float* __restrict__ f, const float* __restrict__ wgt,
                                           const float* __restrict__ W2, const float* __restrict__ b2,
                                           float* __restrict__ out) {
  __shared__ float cw[100];
  __shared__ float ol[200];
  __shared__ float sred[4];
  int bx = blockIdx.x; int n = bx / 20, s = bx % 20;
  int t = threadIdx.x; int w = t >> 6; int lane = t & 63;
  const float* fb = f + ((size_t)n * 20 + s) * 100 * 200;
  for (int bi = w * 25; bi < w * 25 + 25; bi++) {
    const float* fr = fb + bi * 200;
    float v0 = fr[lane], v1 = fr[lane + 64], v2 = fr[lane + 128];
    float v3 = (lane < 8) ? fr[lane + 192] : 0.f;
    float s2 = wred(v0 * v0 + v1 * v1 + v2 * v2 + v3 * v3);
    if (lane == 0) cw[bi] = wgt[n * 2000 + s * 100 + bi] * 2.f / (1.f + s2);
  }
  __syncthreads();
  float o = 0.f;
  if (t < 200) {
    for (int bi = 0; bi < 100; bi++) o += cw[bi] * fb[bi * 200 + t];
  }
  float ps = (t < 200) ? o * o : 0.f;
  ps = wred(ps);
  if (lane == 0) sred[w] = ps;
  __syncthreads();
  float no2 = sred[0] + sred[1] + sred[2] + sred[3];
  float denom = 1.f + sqrtf(1.f + no2);
  if (t < 200) ol[t] = o / denom;
  __syncthreads();
  const float4* ol4 = (const float4*)ol;
#pragma unroll
  for (int jj = 0; jj < 3; jj++) {
    int j = t + 256 * jj;
    const float4* wrow = (const float4*)(W2 + (size_t)j * 200);
    float a0 = 0, a1 = 0, a2 = 0, a3 = 0;
    for (int k4 = 0; k4 < 50; k4++) {
      float4 wv = wrow[k4]; float4 ov = ol4[k4];
      a0 += wv.x * ov.x; a1 += wv.y * ov.y; a2 += wv.z * ov.z; a3 += wv.w * ov.w;
    }
    out[((size_t)n * 20 + s) * 768 + j] = a0 + a1 + a2 + a3 + b2[j];
  }
}

extern "C" void kernel_launch(void* const* d_in, const int* in_sizes, int n_in,
                              void* d_out, int out_size, void* d_ws, size_t ws_size,
                              hipStream_t stream) {
  const float* x_     = (const float*)d_in[0];
  const float* W1     = (const float*)d_in[1];
  const float* b1     = (const float*)d_in[2];
  const float* W2     = (const float*)d_in[3];
  const float* b2     = (const float*)d_in[4];
  const float* Wih_f  = (const float*)d_in[5];
  const float* Whh_f  = (const float*)d_in[6];
  const float* bias_f = (const float*)d_in[7];
  const float* Wih_b  = (const float*)d_in[8];
  const float* Whh_b  = (const float*)d_in[9];
  const float* bias_b = (const float*)d_in[10];
  const float* centroid = (const float*)d_in[11];
  const float* Wp     = (const float*)d_in[12];
  const float* bp     = (const float*)d_in[13];
  const float* beta   = (const float*)d_in[14];
  float* out = (float*)d_out;
  float* ws = (float*)d_ws;
  float* p   = ws + OFF_P;
  float* ux  = ws + OFF_UX;
  float* wt4 = ws + OFF_WT4;
  float* f   = ws + OFF_F;
  float* wi4 = ws + OFF_WI4;
  float* w1p = ws + OFF_W1P;
  float* mx  = ws + OFF_MX;
  float* wp4 = ws + OFF_WP4;
  float* nub = ws + OFF_NUB;
  float* cl  = ws + OFF_CL;
  float* aa  = ws + OFF_A;
  float* gg  = ws + OFF_G;
  float* wg  = ws + OFF_WGT;

  (void)hipFuncSetAttribute(reinterpret_cast<const void*>(k3),
                            hipFuncAttributeMaxDynamicSharedMemorySize, K3_LDS_BYTES);
  (void)hipFuncSetAttribute(reinterpret_cast<const void*>(k2),
                            hipFuncAttributeMaxDynamicSharedMemorySize, K2_LDS_BYTES);
  (void)hipFuncSetAttribute(reinterpret_cast<const void*>(k4ag),
                            hipFuncAttributeMaxDynamicSharedMemorySize, K4G_LDS_BYTES);

  k0_pack<<<925, 256, 0, stream>>>(Whh_f, Whh_b, Wih_f, Wih_b, W1, Wp, wt4, wi4, w1p, wp4);
  k0_cl<<<1, 256, 0, stream>>>(centroid, cl);
  k1<<<500, 256, 0, stream>>>(x_, w1p, b1, p);
  k2<<<3000, 256, K2_LDS_BYTES, stream>>>(p, wi4, ux);
  k2b<<<3000, 256, 0, stream>>>(ux, bias_f, bias_b, nub);
  k3<<<256, 1024, K3_LDS_BYTES, stream>>>(ux, nub, wt4, bias_f, bias_b, f);
  k4ag<<<1000, 256, K4G_LDS_BYTES, stream>>>(f, wp4, mx);
  k4ae<<<500, 256, 0, stream>>>(f, mx, bp, cl, beta, aa, gg);
  k4b<<<16, 256, 0, stream>>>(aa, gg, wg);
  k4c<<<320, 256, 0, stream>>>(f, wg, W2, b2, out);
}

// Round 6
// 1008.309 us; speedup vs baseline: 1.7645x; 1.7645x over previous
//
#include <hip/hip_runtime.h>
#include <hip/hip_bf16.h>

#define MINF 1e-15f
#define EPSF 1e-6f

// ---------- workspace layout (floats) ----------
#define OFF_P    0u            // 16*2000*100      = 3,200,000
#define OFF_UX   3200000u      // 2*3*32000*100    = 19,200,000
#define OFF_WT4  22400000u     // 2*3*25*100*4     = 60,000
#define OFF_F    22460000u     // 16*20*100*200    = 6,400,000
#define OFF_CL   28860000u     // 201 (pad 256)
#define OFF_A    28860256u     // 32000
#define OFF_G    28892256u     // 32000
#define OFF_WGT  28924256u     // 32000
// Region reuse (all stream-ordered, re-packed every call):
//   wi4/w1p live in the f region until k3 overwrites f.
//   mx (raw Wp-GEMM output) reuses the ux region (dead after k3).
//   wp4 reuses the aa/gg region (dead until k4ae writes aa/gg).
//   nub (k2b: |ux|^2 [0,192000) and <ux,b> [192000,384000)) reuses the p
//   region (dead after k2; k2b runs between k2 and k3).
#define OFF_WI4  OFF_F
#define OFF_W1P  (OFF_F + 60000u)
#define OFF_MX   OFF_UX
#define OFF_WP4  OFF_A
#define OFF_NUB  OFF_P

#define K3_LDS_BYTES ((30000 + 2*13*112) * 4)     // W 120000 + hl/rhl 11648 = 131648
#define K2_LDS_BYTES ((3200 + 64*26)*16 + 64*4)   // W 51200 + p 26624 + alx 256 = 78080
#define K4G_LDS_BYTES ((3200 + 64*26)*16)         // W 51200 + f 26624 = 77824

__device__ __forceinline__ float wred(float v) {
#pragma unroll
  for (int m = 32; m > 0; m >>= 1) v += __shfl_xor(v, m, 64);
  return v;
}
__device__ __forceinline__ float wredmax(float v) {
#pragma unroll
  for (int m = 32; m > 0; m >>= 1) v = fmaxf(v, __shfl_xor(v, m, 64));
  return v;
}
__device__ __forceinline__ float artanh_c(float x) {
  x = fminf(x, 1.f - 1e-7f);
  return 0.5f * (log1pf(x) - log1pf(-x));
}
__device__ __forceinline__ float arcosh_(float x) {
  return logf(x) + log1pf(sqrtf(fmaxf(x * x - 1.f + EPSF, 0.f)) / x);
}
__device__ __forceinline__ float sigm(float x) { return 1.f / (1.f + expf(-x)); }

// ---------------- K0a: pack weights into float4-friendly layouts ----------------
__global__ void k0_pack(const float* __restrict__ whh_f, const float* __restrict__ whh_b,
                        const float* __restrict__ wih_f, const float* __restrict__ wih_b,
                        const float* __restrict__ W1, const float* __restrict__ Wp,
                        float* __restrict__ wt4, float* __restrict__ wi4,
                        float* __restrict__ w1p, float* __restrict__ wp4) {
  int idx = blockIdx.x * 256 + threadIdx.x;
  if (idx < 60000) {
    int kk = idx & 3; int t = idx >> 2;
    int j = t % 100; t /= 100;
    int k4 = t % 25; t /= 25;
    int g = t % 3; int dir = t / 3;
    const float* src = dir ? whh_b : whh_f;
    wt4[idx] = src[g * 10000 + j * 100 + k4 * 4 + kk];
  } else if (idx < 120000) {
    int i2 = idx - 60000;
    int kk = i2 & 3; int t = i2 >> 2;
    int c = t % 100; t /= 100;
    int k4 = t % 25; t /= 25;
    int g = t % 3; int dir = t / 3;
    const float* src = dir ? wih_b : wih_f;
    wi4[i2] = src[g * 10000 + c * 100 + k4 * 4 + kk];
  } else if (idx < 196800) {
    int i2 = idx - 120000;
    int kk = i2 & 3; int t = i2 >> 2;
    int c = t % 100; int k4 = t / 100;
    w1p[i2] = W1[c * 768 + k4 * 4 + kk];
  } else if (idx < 236800) {
    int i3 = idx - 196800;
    int kk = i3 & 3; int t = i3 >> 2;
    int c = t % 100; int t2 = t / 100;
    int k4 = t2 % 50; int ch = t2 / 50;
    wp4[i3] = Wp[(size_t)(ch * 100 + c) * 200 + k4 * 4 + kk];
  }
}

// ---------------- K0b: lorentz_activation(centroid) -> cl[201] ----------------
__global__ void k0_cl(const float* __restrict__ centroid, float* __restrict__ cl) {
  __shared__ float sred[4];
  int t = threadIdx.x;
  float v = (t < 200) ? centroid[t] : 0.f;
  float ps = wred(v * v);
  if ((t & 63) == 0) sred[t >> 6] = ps;
  __syncthreads();
  float r = sqrtf(sred[0] + sred[1] + sred[2] + sred[3]);
  if (t < 200) cl[t] = v / r * sinhf(r);
  if (t == 0) cl[200] = coshf(r);
}

// ---------------- K1: klein(x_) @ W1^T + b1, poincare project -> p ----------------
__global__ __launch_bounds__(256, 2) void k1(const float* __restrict__ x_,
                                             const float* __restrict__ w1p,
                                             const float* __restrict__ b1,
                                             float* __restrict__ p) {
  __shared__ float4 wl[16 * 128];
  __shared__ float4 xl[64 * 16];
  __shared__ float ns[64];
  __shared__ float sscale[64];
  int t = threadIdx.x;
  int row0 = blockIdx.x * 64;
  int cg = t & 31, rg = t >> 5;
  const float4* wsrc = (const float4*)w1p;
  float nacc[4] = {0, 0, 0, 0};
  float acc[8][4] = {};
  for (int kc = 0; kc < 12; kc++) {
    int k0f4 = kc * 16;
    __syncthreads();
#pragma unroll
    for (int q = 0; q < 4; q++) {
      int idx = t + 256 * q;
      int r = idx >> 4, c4 = idx & 15;
      float4 v = *(const float4*)(x_ + (size_t)(row0 + r) * 768 + (size_t)(k0f4 + c4) * 4);
      xl[idx] = v;
      nacc[q] += v.x * v.x + v.y * v.y + v.z * v.z + v.w * v.w;
    }
#pragma unroll
    for (int q = 0; q < 8; q++) {
      int idx = t + 256 * q;
      int k4 = idx >> 7, c = idx & 127;
      float4 v = {0, 0, 0, 0};
      if (c < 100) v = wsrc[(size_t)(k0f4 + k4) * 100 + c];
      wl[idx] = v;
    }
    __syncthreads();
#pragma unroll 4
    for (int k4 = 0; k4 < 16; k4++) {
      float4 wv[4];
#pragma unroll
      for (int j = 0; j < 4; j++) wv[j] = wl[k4 * 128 + cg + 32 * j];
#pragma unroll
      for (int i = 0; i < 8; i++) {
        float4 pv = xl[(rg * 8 + i) * 16 + k4];
#pragma unroll
        for (int j = 0; j < 4; j++)
          acc[i][j] += pv.x * wv[j].x + pv.y * wv[j].y + pv.z * wv[j].z + pv.w * wv[j].w;
      }
    }
  }
  __syncthreads();
#pragma unroll
  for (int q = 0; q < 4; q++) {
    float v = nacc[q];
#pragma unroll
    for (int m = 8; m > 0; m >>= 1) v += __shfl_xor(v, m, 64);
    if ((t & 15) == 0) ns[(t >> 4) + 16 * q] = v;
  }
  __syncthreads();
  if (t < 64) {
    float rr = sqrtf(fmaxf(ns[t], MINF));
    sscale[t] = tanhf(rr) / rr;
  }
  __syncthreads();
  float bcol[4];
#pragma unroll
  for (int j = 0; j < 4; j++) {
    int col = cg + 32 * j;
    bcol[j] = (col < 100) ? b1[col] : 0.f;
  }
#pragma unroll
  for (int i = 0; i < 8; i++) {
    int r = rg * 8 + i;
    float s = sscale[r];
    float hv[4]; float ss = 0.f;
#pragma unroll
    for (int j = 0; j < 4; j++) {
      int col = cg + 32 * j;
      hv[j] = (col < 100) ? (s * acc[i][j] + bcol[j]) : 0.f;
      ss += hv[j] * hv[j];
    }
#pragma unroll
    for (int m = 16; m > 0; m >>= 1) ss += __shfl_xor(ss, m, 64);
    float inv = 1.f / sqrtf(1.f + ss);
    float* prow = p + (size_t)(row0 + r) * 100;
#pragma unroll
    for (int j = 0; j < 4; j++) {
      int col = cg + 32 * j;
      if (col < 100) prow[col] = hv[j] * inv;
    }
  }
}

// ---------------- K2: ux[combo][row] = m_matvec(Wih_combo, p[row]) ----------------
__global__ __launch_bounds__(256, 2) void k2(const float* __restrict__ p,
                                             const float* __restrict__ wi4,
                                             float* __restrict__ ux) {
  extern __shared__ float4 l4[];
  float4* wl = l4;
  float4* pl = l4 + 3200;
  float* alx = (float*)(l4 + 3200 + 64 * 26);
  int t = threadIdx.x;
  int bx = blockIdx.x;
  int combo = bx / 500, tile = bx % 500;
  int row0 = tile * 64;
  int cg = t & 31, rg = t >> 5;
  const float4* wsrc = (const float4*)wi4 + (size_t)combo * 2500;
#pragma unroll
  for (int q = 0; q < 13; q++) {
    int idx = t + 256 * q;
    if (idx < 3200) {
      int k4 = idx >> 7, c = idx & 127;
      float4 v = {0, 0, 0, 0};
      if (c < 100) v = wsrc[k4 * 100 + c];
      wl[idx] = v;
    }
  }
  const float4* psrc = (const float4*)(p + (size_t)row0 * 100);
#pragma unroll
  for (int q = 0; q < 7; q++) {
    int idx = t + 256 * q;
    if (idx < 1600) {
      int r = idx / 25, c4 = idx % 25;
      pl[r * 26 + c4] = psrc[idx];
    }
  }
  __syncthreads();
  {
    int w = t >> 6, lane = t & 63;
    const float* pf = (const float*)pl;
    for (int r = w * 16; r < w * 16 + 16; r++) {
      float v0 = pf[r * 104 + lane];
      float v1 = (lane < 36) ? pf[r * 104 + 64 + lane] : 0.f;
      float s2 = wred(v0 * v0 + v1 * v1);
      if (lane == 0) {
        float xn = sqrtf(fmaxf(s2, MINF));
        alx[r] = artanh_c(xn) / xn;
      }
    }
  }
  __syncthreads();
  float acc[8][4] = {};
#pragma unroll 5
  for (int k4 = 0; k4 < 25; k4++) {
    float4 wv[4];
#pragma unroll
    for (int j = 0; j < 4; j++) wv[j] = wl[k4 * 128 + cg + 32 * j];
#pragma unroll
    for (int i = 0; i < 8; i++) {
      float4 pv = pl[(rg * 8 + i) * 26 + k4];
#pragma unroll
      for (int j = 0; j < 4; j++)
        acc[i][j] += pv.x * wv[j].x + pv.y * wv[j].y + pv.z * wv[j].z + pv.w * wv[j].w;
    }
  }
#pragma unroll
  for (int i = 0; i < 8; i++) {
    int r = rg * 8 + i;
    float ss = acc[i][0] * acc[i][0] + acc[i][1] * acc[i][1] +
               acc[i][2] * acc[i][2] + acc[i][3] * acc[i][3];
#pragma unroll
    for (int m = 16; m > 0; m >>= 1) ss += __shfl_xor(ss, m, 64);
    float mxn = sqrtf(fmaxf(ss, MINF));
    float sc = tanhf(mxn * alx[r]) / mxn;
    float* dst = ux + ((size_t)combo * 32000 + row0 + r) * 100;
#pragma unroll
    for (int j = 0; j < 4; j++) {
      int col = cg + 32 * j;
      if (col < 100) dst[col] = sc * acc[i][j];
    }
  }
}

// ---------------- K2b: per-(combo,row) |ux|^2 and <ux,bias_g> ----------------
__global__ __launch_bounds__(256) void k2b(const float* __restrict__ ux,
                                           const float* __restrict__ bias_f,
                                           const float* __restrict__ bias_b,
                                           float* __restrict__ nub) {
  int t = threadIdx.x; int w = t >> 6; int lane = t & 63;
  int gr0 = blockIdx.x * 64;
  int combo = gr0 / 32000;
  int dir = combo / 3, g = combo % 3;
  const float* bias = (dir ? bias_b : bias_f) + g * 100;
  float b0 = bias[lane];
  float b1 = (lane < 36) ? bias[64 + lane] : 0.f;
  for (int i = w * 16; i < w * 16 + 16; i++) {
    const float* u = ux + (size_t)(gr0 + i) * 100;
    float u0 = u[lane];
    float u1 = (lane < 36) ? u[64 + lane] : 0.f;
    float n2 = wred(u0 * u0 + u1 * u1);
    float ub = wred(u0 * b0 + u1 * b1);
    if (lane == 0) { nub[gr0 + i] = n2; nub[192000 + gr0 + i] = ub; }
  }
}

// ---------------- K3: sequential Mobius GRU — wave-private, barrier-free ----------------
// Matvec outputs stay in registers: the producer wave IS the consumer wave, and
// lane L's accumulator sum IS output element L. No mvl LDS round-trip, no
// per-step __syncthreads (hl/rhl row w touched only by wave w).
__device__ __forceinline__ void mv100x2_reg(const float* __restrict__ Wz,
                                            const float* __restrict__ Wr,
                                            const float* __restrict__ hrow,
                                            int lane, bool hi,
                                            float& mz0, float& mz1,
                                            float& mr0, float& mr1) {
  const float4* Wz4 = (const float4*)Wz;
  const float4* Wr4 = (const float4*)Wr;
  const float4* h4 = (const float4*)hrow;
  float4 az0 = {0, 0, 0, 0}, az1 = {0, 0, 0, 0};
  float4 ar0 = {0, 0, 0, 0}, ar1 = {0, 0, 0, 0};
#pragma unroll 5
  for (int k4 = 0; k4 < 25; k4++) {
    float4 hv = h4[k4];
    float4 wz = Wz4[k4 * 100 + lane];
    float4 wr = Wr4[k4 * 100 + lane];
    az0.x += wz.x * hv.x; az0.y += wz.y * hv.y; az0.z += wz.z * hv.z; az0.w += wz.w * hv.w;
    ar0.x += wr.x * hv.x; ar0.y += wr.y * hv.y; ar0.z += wr.z * hv.z; ar0.w += wr.w * hv.w;
    if (hi) {
      float4 wzh = Wz4[k4 * 100 + 64 + lane];
      float4 wrh = Wr4[k4 * 100 + 64 + lane];
      az1.x += wzh.x * hv.x; az1.y += wzh.y * hv.y; az1.z += wzh.z * hv.z; az1.w += wzh.w * hv.w;
      ar1.x += wrh.x * hv.x; ar1.y += wrh.y * hv.y; ar1.z += wrh.z * hv.z; ar1.w += wrh.w * hv.w;
    }
  }
  mz0 = az0.x + az0.y + az0.z + az0.w;
  mr0 = ar0.x + ar0.y + ar0.z + ar0.w;
  mz1 = az1.x + az1.y + az1.z + az1.w;
  mr1 = ar1.x + ar1.y + ar1.z + ar1.w;
}

__device__ __forceinline__ void mv100_reg(const float* __restrict__ Wg,
                                          const float* __restrict__ hrow,
                                          int lane, bool hi,
                                          float& m0, float& m1) {
  const float4* W4 = (const float4*)Wg;
  const float4* h4 = (const float4*)hrow;
  float4 a0 = {0, 0, 0, 0}, a1 = {0, 0, 0, 0};
#pragma unroll 5
  for (int k4 = 0; k4 < 25; k4++) {
    float4 hv = h4[k4];
    float4 w0 = W4[k4 * 100 + lane];
    a0.x += w0.x * hv.x; a0.y += w0.y * hv.y; a0.z += w0.z * hv.z; a0.w += w0.w * hv.w;
    if (hi) {
      float4 w1 = W4[k4 * 100 + 64 + lane];
      a1.x += w1.x * hv.x; a1.y += w1.y * hv.y; a1.z += w1.z * hv.z; a1.w += w1.w * hv.w;
    }
  }
  m0 = a0.x + a0.y + a0.z + a0.w;
  m1 = a1.x + a1.y + a1.z + a1.w;
}

// onetrans via scalar identities (r5-verified): A=|m|^2, B=<m,ux>, Mb=<m,b>
// are the only wreds; C=|ux|^2, ub=<ux,b> precomputed (k2b); D, E, F scalar.
__device__ __forceinline__ void gate_ot(float m0, float m1, float u0, float u1,
                                        float b0v, float b1v, float C, float ub, float nb2,
                                        float alphah,
                                        float& c0, float& c1, float& Fout) {
  float A = wred(m0 * m0 + m1 * m1);
  float B = wred(m0 * u0 + m1 * u1);
  float Mb = wred(m0 * b0v + m1 * b1v);
  float mxn = sqrtf(fmaxf(A, MINF));
  float gam = tanhf(mxn * alphah) / mxn;
  float x2 = gam * gam * A, xy = gam * B;
  float rd = 1.f / fmaxf(1.f + 2.f * xy + x2 * C, MINF);
  float cA = (1.f + 2.f * xy + C) * gam * rd, cB = (1.f - x2) * rd;
  float D = fmaxf(cA * cA * A + 2.f * cA * cB * B + cB * cB * C, 0.f);
  float E = cA * Mb + cB * ub;
  float r2 = 1.f / fmaxf(1.f + 2.f * E + D * nb2, MINF);
  float t1 = (1.f + 2.f * E + nb2) * r2, t2 = (1.f - D) * r2;
  c0 = t1 * (cA * m0 + cB * u0) + t2 * b0v;
  c1 = t1 * (cA * m1 + cB * u1) + t2 * b1v;
  Fout = fmaxf(t1 * t1 * D + 2.f * t1 * t2 * E + t2 * t2 * nb2, MINF);
}

// grid 256 (32 groups x 8 row-chunks), block 1024 (13 live waves), LDS 131648 B.
// __launch_bounds__(1024, 1): flat-workgroup-size 1024 bounds VGPRs at 128 for
// launchability; min=1 avoids the 64-VGPR clamp that caused r5's 822 MB spill.
__global__ __launch_bounds__(1024, 1) void k3(const float* __restrict__ ux,
                                              const float* __restrict__ nub,
                                              const float* __restrict__ wt4,
                                              const float* __restrict__ bias_f,
                                              const float* __restrict__ bias_b,
                                              float* __restrict__ f) {
  extern __shared__ float lds[];
  float* Wlds = lds;                 // 30000
  float* hl = lds + 30000;           // 13*112
  float* rhl = hl + 13 * 112;        // 13*112
  int t = threadIdx.x; int w = t >> 6; int lane = t & 63;
  bool hi = lane < 36;
  int bx = blockIdx.x;
  int grp = bx >> 3; int blki = bx & 7;
  int n = grp >> 1; int dir = grp & 1;
  int b0 = blki * 13; int nrows = min(13, 100 - b0);
  const float* bias = dir ? bias_b : bias_f;
  const float* wsrc = wt4 + dir * 30000;
#pragma unroll
  for (int q = 0; q < 30; q++) { int idx = t + 1024 * q; if (idx < 30000) Wlds[idx] = wsrc[idx]; }
  int row = w; bool erow = (w < nrows);
  if (erow) {   // zero own h row (wave-private; read first by this wave only)
    hl[row * 112 + lane] = 0.f;
    if (hi) hl[row * 112 + 64 + lane] = 0.f;
  }
  __syncthreads();   // Wlds ready — the ONLY barrier in the kernel
  if (!erow) return;

  int b = b0 + row;
  float nh2 = 0.f, h0 = 0.f, h1 = 0.f;
  float br0 = bias[lane],       br1 = hi ? bias[64 + lane] : 0.f;
  float bh0 = bias[100 + lane], bh1 = hi ? bias[164 + lane] : 0.f;
  float bz0 = bias[200 + lane], bz1 = hi ? bias[264 + lane] : 0.f;
  float nbr2 = wred(br0 * br0 + br1 * br1);
  float nbh2 = wred(bh0 * bh0 + bh1 * bh1);
  float nbz2 = wred(bz0 * bz0 + bz1 * bz1);

  for (int s = 0; s < 20; s++) {
    // ---- M1: z+r matvecs on own row, results stay in registers ----
    float mz0, mz1, mr0, mr1;
    mv100x2_reg(Wlds + 2 * 10000, Wlds + 0 * 10000, hl + row * 112, lane, hi,
                mz0, mz1, mr0, mr1);
    // ---- per-step inputs ----
    int l = dir ? (1999 - (s * 100 + b)) : (s * 100 + b);
    size_t rowg = (size_t)n * 2000 + l;
    size_t iz = (size_t)(dir * 3 + 2) * 32000 + rowg;
    size_t ir = (size_t)(dir * 3 + 0) * 32000 + rowg;
    size_t ih = (size_t)(dir * 3 + 1) * 32000 + rowg;
    const float* uxz = ux + iz * 100;
    const float* uxr = ux + ir * 100;
    const float* uxhp = ux + ih * 100;
    float uz0 = uxz[lane],  uz1 = hi ? uxz[lane + 64] : 0.f;
    float ur0 = uxr[lane],  ur1 = hi ? uxr[lane + 64] : 0.f;
    float uxh0 = uxhp[lane], uxh1 = hi ? uxhp[lane + 64] : 0.f;
    float Cz = nub[iz], ubz = nub[192000 + iz];
    float Cr = nub[ir], ubr = nub[192000 + ir];
    float Ch = nub[ih], ubh = nub[192000 + ih];
    // ---- z, r gates + rh ----
    float xnh = sqrtf(fmaxf(nh2, MINF));
    float alphah = artanh_c(xnh) / xnh;
    float cz0, cz1, Fz, cr0, cr1, Fr;
    gate_ot(mz0, mz1, uz0, uz1, bz0, bz1, Cz, ubz, nbz2, alphah, cz0, cz1, Fz);
    gate_ot(mr0, mr1, ur0, ur1, br0, br1, Cr, ubr, nbr2, alphah, cr0, cr1, Fr);
    float cnz = sqrtf(Fz); float lgz = artanh_c(cnz) / cnz;
    float z0 = sigm(lgz * cz0), z1 = sigm(lgz * cz1);
    float cnr = sqrtf(Fr); float lgr = artanh_c(cnr) / cnr;
    float rg0 = sigm(lgr * cr0), rg1 = sigm(lgr * cr1);
    float mx0 = rg0 * h0, mx1 = rg1 * h1;
    float G = wred(mx0 * mx0 + mx1 * mx1);
    float mxnr = sqrtf(fmaxf(G, MINF));
    float srh = tanhf(mxnr * alphah) / mxnr;
    rhl[row * 112 + lane] = srh * mx0;
    if (hi) rhl[row * 112 + lane + 64] = srh * mx1;
    float nrh2 = srh * srh * G;
    // ---- M2: htil matvec on own row (same wave wrote rhl; no barrier) ----
    float mh0, mh1;
    mv100_reg(Wlds + 1 * 10000, rhl + row * 112, lane, hi, mh0, mh1);
    // ---- htil, d, pw, hn ----
    float xnrh = sqrtf(fmaxf(nrh2, MINF));
    float alpharh = artanh_c(xnrh) / xnrh;
    float ct0, ct1, T;
    gate_ot(mh0, mh1, uxh0, uxh1, bh0, bh1, Ch, ubh, nbh2, alpharh, ct0, ct1, T);
    float U = wred(h0 * ct0 + h1 * ct1);
    float rdd = 1.f / fmaxf(1.f - 2.f * U + nh2 * T, MINF);
    float cAd = (1.f - 2.f * U + T) * rdd, cBd = (1.f - nh2) * rdd;
    float d0 = -cAd * h0 + cBd * ct0, d1 = -cAd * h1 + cBd * ct1;
    float nd2 = fmaxf(cAd * cAd * nh2 - 2.f * cAd * cBd * U + cBd * cBd * T, MINF);
    float zd0 = z0 * d0, zd1 = z1 * d1;
    float P = wred(zd0 * zd0 + zd1 * zd1);
    float Q = wred(h0 * zd0 + h1 * zd1);
    float xnd = sqrtf(nd2);
    float mxnp = sqrtf(fmaxf(P, MINF));
    float sp = tanhf(mxnp * artanh_c(xnd) / xnd) / mxnp;
    float y2p = sp * sp * P, xyp = sp * Q;
    float r3 = 1.f / fmaxf(1.f + 2.f * xyp + nh2 * y2p, MINF);
    float A1 = (1.f + 2.f * xyp + y2p) * r3, B1 = (1.f - nh2) * r3 * sp;
    float hn0 = A1 * h0 + B1 * zd0, hn1 = A1 * h1 + B1 * zd1;
    nh2 = fmaxf(A1 * A1 * nh2 + 2.f * A1 * B1 * Q + B1 * B1 * P, 0.f);
    h0 = hn0; h1 = hn1;
    hl[row * 112 + lane] = hn0;
    if (hi) hl[row * 112 + lane + 64] = hn1;
    float* fd = f + (((size_t)n * 20 + s) * 100 + b) * 200 + dir * 100;
    fd[lane] = hn0;
    if (hi) fd[lane + 64] = hn1;
  }
}

// ---------------- K4ag: mx = f @ Wp^T (raw), register-tiled ----------------
__global__ __launch_bounds__(256, 2) void k4ag(const float* __restrict__ f,
                                               const float* __restrict__ wp4,
                                               float* __restrict__ mx) {
  extern __shared__ float4 g4[];
  float4* wl = g4;
  float4* pl = g4 + 3200;
  int t = threadIdx.x;
  int bx = blockIdx.x;
  int ch = bx & 1, tile = bx >> 1;
  int row0 = tile * 64;
  int cg = t & 31, rg = t >> 5;
  const float4* wsrc = (const float4*)wp4 + (size_t)ch * 5000;
  const float4* psrc = (const float4*)(f + (size_t)row0 * 200);
  float acc[8][4] = {};
  for (int kc = 0; kc < 2; kc++) {
    __syncthreads();
#pragma unroll
    for (int q = 0; q < 13; q++) {
      int idx = t + 256 * q;
      if (idx < 3200) {
        int k4 = idx >> 7, c = idx & 127;
        float4 v = {0, 0, 0, 0};
        if (c < 100) v = wsrc[(kc * 25 + k4) * 100 + c];
        wl[idx] = v;
      }
    }
#pragma unroll
    for (int q = 0; q < 7; q++) {
      int idx = t + 256 * q;
      if (idx < 1600) {
        int r = idx / 25, k4 = idx % 25;
        pl[r * 26 + k4] = psrc[r * 50 + kc * 25 + k4];
      }
    }
    __syncthreads();
#pragma unroll 5
    for (int k4 = 0; k4 < 25; k4++) {
      float4 wv[4];
#pragma unroll
      for (int j = 0; j < 4; j++) wv[j] = wl[k4 * 128 + cg + 32 * j];
#pragma unroll
      for (int i = 0; i < 8; i++) {
        float4 pv = pl[(rg * 8 + i) * 26 + k4];
#pragma unroll
        for (int j = 0; j < 4; j++)
          acc[i][j] += pv.x * wv[j].x + pv.y * wv[j].y + pv.z * wv[j].z + pv.w * wv[j].w;
      }
    }
  }
#pragma unroll
  for (int i = 0; i < 8; i++) {
    float* dst = mx + (size_t)(row0 + rg * 8 + i) * 200 + ch * 100;
#pragma unroll
    for (int j = 0; j < 4; j++) {
      int col = cg + 32 * j;
      if (col < 100) dst[col] = acc[i][j];
    }
  }
}

// ---------------- K4ae: Mobius m_add(bp) + lorentz logits a, gamma ----------------
__global__ __launch_bounds__(256) void k4ae(const float* __restrict__ f,
                                            const float* __restrict__ mx,
                                            const float* __restrict__ bp,
                                            const float* __restrict__ cl,
                                            const float* __restrict__ beta_p,
                                            float* __restrict__ a_out, float* __restrict__ g_out) {
  int t = threadIdx.x; int w = t >> 6; int lane = t & 63;
  int row0 = blockIdx.x * 64;
  float beta = beta_p[0];
  float c200 = cl[200];
  float b_0 = bp[lane], b_1 = bp[lane + 64], b_2 = bp[lane + 128];
  float b_3 = (lane < 8) ? bp[lane + 192] : 0.f;
  float c_0 = cl[lane], c_1 = cl[lane + 64], c_2 = cl[lane + 128];
  float c_3 = (lane < 8) ? cl[lane + 192] : 0.f;
  float nbp2 = wred(b_0 * b_0 + b_1 * b_1 + b_2 * b_2 + b_3 * b_3);
  for (int r = w * 16; r < w * 16 + 16; r++) {
    const float* fr = f + (size_t)(row0 + r) * 200;
    const float* mr = mx + (size_t)(row0 + r) * 200;
    float f0 = fr[lane], f1 = fr[lane + 64], f2 = fr[lane + 128];
    float f3 = (lane < 8) ? fr[lane + 192] : 0.f;
    float nf2 = wred(f0 * f0 + f1 * f1 + f2 * f2 + f3 * f3);
    float xn = sqrtf(fmaxf(nf2, MINF));
    float alx = artanh_c(xn) / xn;
    float m0 = mr[lane], m1 = mr[lane + 64], m2 = mr[lane + 128];
    float m3 = (lane < 8) ? mr[lane + 192] : 0.f;
    float A = wred(m0 * m0 + m1 * m1 + m2 * m2 + m3 * m3);
    float B = wred(m0 * b_0 + m1 * b_1 + m2 * b_2 + m3 * b_3);
    float mxn = sqrtf(fmaxf(A, MINF));
    float gam = tanhf(mxn * alx) / mxn;
    float x2 = gam * gam * A, y2 = nbp2, xy = gam * B;
    float rd = 1.f / fmaxf(1.f + 2.f * xy + x2 * y2, MINF);
    float cA = (1.f + 2.f * xy + y2) * gam * rd, cB = (1.f - x2) * rd;
    float a0 = cA * m0 + cB * b_0, a1 = cA * m1 + cB * b_1;
    float a2 = cA * m2 + cB * b_2, a3 = cA * m3 + cB * b_3;
    float r2 = wred(a0 * a0 + a1 * a1 + a2 * a2 + a3 * a3);
    float dc = wred(a0 * c_0 + a1 * c_1 + a2 * c_2 + a3 * c_3);
    float pm = (-2.f * dc + (1.f + r2) * c200) / (1.f - r2 + EPSF);
    pm = fminf(fmaxf(pm, 1.f + EPSF), 1e16f);
    float av = -beta * arcosh_(pm) - 1.f;
    float invg = 1.f - 4.f * nf2 / ((1.f + nf2) * (1.f + nf2));
    invg = fminf(fmaxf(invg, EPSF), 1.f - EPSF);
    float gv = fminf(fmaxf(1.f / sqrtf(invg), 1.f + EPSF), 1e16f);
    if (lane == 0) { a_out[row0 + r] = av; g_out[row0 + r] = gv; }
  }
}

// ---------------- K4b: per-sample softmax weights ----------------
__global__ __launch_bounds__(256) void k4b(const float* __restrict__ a_in,
                                           const float* __restrict__ g_in,
                                           float* __restrict__ wgt) {
  __shared__ float rl[2000];
  __shared__ float sred[4];
  __shared__ float rsinv[100];
  int n = blockIdx.x; int t = threadIdx.x;
  int w = t >> 6, lane = t & 63;
  const float* ap = a_in + n * 2000;
  const float* gp = g_in + n * 2000;
  float av[8]; float am = -1e30f;
#pragma unroll
  for (int q = 0; q < 8; q++) {
    int i = t + 256 * q;
    av[q] = (i < 2000) ? ap[i] : -1e30f;
    am = fmaxf(am, av[q]);
  }
  am = wredmax(am);
  if (lane == 0) sred[w] = am;
  __syncthreads();
  float amax = fmaxf(fmaxf(sred[0], sred[1]), fmaxf(sred[2], sred[3]));
#pragma unroll
  for (int q = 0; q < 8; q++) {
    int i = t + 256 * q;
    if (i < 2000) rl[i] = expf(av[q] - amax) * gp[i];
  }
  __syncthreads();
  if (t < 100) {
    float ssum = 0.f;
#pragma unroll
    for (int s = 0; s < 20; s++) ssum += rl[s * 100 + t];
    rsinv[t] = 1.f / ssum;
  }
  __syncthreads();
#pragma unroll
  for (int q = 0; q < 8; q++) {
    int i = t + 256 * q;
    if (i < 2000) wgt[n * 2000 + i] = rl[i] * rsinv[i % 100];
  }
}

// ---------------- K4c: klein aggregation + final GEMM W2 ----------------
__global__ __launch_bounds__(256) void k4c(const float* __restrict__ f, const float* __restrict__ wgt,
                                           const float* __restrict__ W2, const float* __restrict__ b2,
                                           float* __restrict__ out) {
  __shared__ float cw[100];
  __shared__ float ol[200];
  __shared__ float sred[4];
  int bx = blockIdx.x; int n = bx / 20, s = bx % 20;
  int t = threadIdx.x; int w = t >> 6; int lane = t & 63;
  const float* fb = f + ((size_t)n * 20 + s) * 100 * 200;
  for (int bi = w * 25; bi < w * 25 + 25; bi++) {
    const float* fr = fb + bi * 200;
    float v0 = fr[lane], v1 = fr[lane + 64], v2 = fr[lane + 128];
    float v3 = (lane < 8) ? fr[lane + 192] : 0.f;
    float s2 = wred(v0 * v0 + v1 * v1 + v2 * v2 + v3 * v3);
    if (lane == 0) cw[bi] = wgt[n * 2000 + s * 100 + bi] * 2.f / (1.f + s2);
  }
  __syncthreads();
  float o = 0.f;
  if (t < 200) {
    for (int bi = 0; bi < 100; bi++) o += cw[bi] * fb[bi * 200 + t];
  }
  float ps = (t < 200) ? o * o : 0.f;
  ps = wred(ps);
  if (lane == 0) sred[w] = ps;
  __syncthreads();
  float no2 = sred[0] + sred[1] + sred[2] + sred[3];
  float denom = 1.f + sqrtf(1.f + no2);
  if (t < 200) ol[t] = o / denom;
  __syncthreads();
  const float4* ol4 = (const float4*)ol;
#pragma unroll
  for (int jj = 0; jj < 3; jj++) {
    int j = t + 256 * jj;
    const float4* wrow = (const float4*)(W2 + (size_t)j * 200);
    float a0 = 0, a1 = 0, a2 = 0, a3 = 0;
    for (int k4 = 0; k4 < 50; k4++) {
      float4 wv = wrow[k4]; float4 ov = ol4[k4];
      a0 += wv.x * ov.x; a1 += wv.y * ov.y; a2 += wv.z * ov.z; a3 += wv.w * ov.w;
    }
    out[((size_t)n * 20 + s) * 768 + j] = a0 + a1 + a2 + a3 + b2[j];
  }
}

extern "C" void kernel_launch(void* const* d_in, const int* in_sizes, int n_in,
                              void* d_out, int out_size, void* d_ws, size_t ws_size,
                              hipStream_t stream) {
  const float* x_     = (const float*)d_in[0];
  const float* W1     = (const float*)d_in[1];
  const float* b1     = (const float*)d_in[2];
  const float* W2     = (const float*)d_in[3];
  const float* b2     = (const float*)d_in[4];
  const float* Wih_f  = (const float*)d_in[5];
  const float* Whh_f  = (const float*)d_in[6];
  const float* bias_f = (const float*)d_in[7];
  const float* Wih_b  = (const float*)d_in[8];
  const float* Whh_b  = (const float*)d_in[9];
  const float* bias_b = (const float*)d_in[10];
  const float* centroid = (const float*)d_in[11];
  const float* Wp     = (const float*)d_in[12];
  const float* bp     = (const float*)d_in[13];
  const float* beta   = (const float*)d_in[14];
  float* out = (float*)d_out;
  float* ws = (float*)d_ws;
  float* p   = ws + OFF_P;
  float* ux  = ws + OFF_UX;
  float* wt4 = ws + OFF_WT4;
  float* f   = ws + OFF_F;
  float* wi4 = ws + OFF_WI4;
  float* w1p = ws + OFF_W1P;
  float* mx  = ws + OFF_MX;
  float* wp4 = ws + OFF_WP4;
  float* nub = ws + OFF_NUB;
  float* cl  = ws + OFF_CL;
  float* aa  = ws + OFF_A;
  float* gg  = ws + OFF_G;
  float* wg  = ws + OFF_WGT;

  (void)hipFuncSetAttribute(reinterpret_cast<const void*>(k3),
                            hipFuncAttributeMaxDynamicSharedMemorySize, K3_LDS_BYTES);
  (void)hipFuncSetAttribute(reinterpret_cast<const void*>(k2),
                            hipFuncAttributeMaxDynamicSharedMemorySize, K2_LDS_BYTES);
  (void)hipFuncSetAttribute(reinterpret_cast<const void*>(k4ag),
                            hipFuncAttributeMaxDynamicSharedMemorySize, K4G_LDS_BYTES);

  k0_pack<<<925, 256, 0, stream>>>(Whh_f, Whh_b, Wih_f, Wih_b, W1, Wp, wt4, wi4, w1p, wp4);
  k0_cl<<<1, 256, 0, stream>>>(centroid, cl);
  k1<<<500, 256, 0, stream>>>(x_, w1p, b1, p);
  k2<<<3000, 256, K2_LDS_BYTES, stream>>>(p, wi4, ux);
  k2b<<<3000, 256, 0, stream>>>(ux, bias_f, bias_b, nub);
  k3<<<256, 1024, K3_LDS_BYTES, stream>>>(ux, nub, wt4, bias_f, bias_b, f);
  k4ag<<<1000, 256, K4G_LDS_BYTES, stream>>>(f, wp4, mx);
  k4ae<<<500, 256, 0, stream>>>(f, mx, bp, cl, beta, aa, gg);
  k4b<<<16, 256, 0, stream>>>(aa, gg, wg);
  k4c<<<320, 256, 0, stream>>>(f, wg, W2, b2, out);
}

// Round 7
// 783.041 us; speedup vs baseline: 2.2721x; 1.2877x over previous
//
#include <hip/hip_runtime.h>
#include <hip/hip_bf16.h>

#define MINF 1e-15f
#define EPSF 1e-6f

// ---------- workspace layout (floats) ----------
#define OFF_P    0u            // 16*2000*100      = 3,200,000
#define OFF_UX   3200000u      // 2*3*32000*100    = 19,200,000
#define OFF_WT4  22400000u     // 2*3*25*100*4     = 60,000
#define OFF_F    22460000u     // 16*20*100*200    = 6,400,000
#define OFF_CL   28860000u     // 201 (pad 256)
#define OFF_A    28860256u     // 32000
#define OFF_G    28892256u     // 32000
#define OFF_WGT  28924256u     // 32000
#define OFF_WI4  OFF_F
#define OFF_W1P  (OFF_F + 60000u)
#define OFF_MX   OFF_UX
#define OFF_WP4  OFF_A
#define OFF_NUB  OFF_P

#define K3_LDS_BYTES ((30000 + 2*13*112) * 4)     // W 120000 + hl/rhl 11648 = 131648
#define K2_LDS_BYTES ((3200 + 64*26)*16 + 64*4)   // W 51200 + p 26624 + alx 256 = 78080
#define K4G_LDS_BYTES ((3200 + 64*26)*16)         // W 51200 + f 26624 = 77824

__device__ __forceinline__ float wred(float v) {
#pragma unroll
  for (int m = 32; m > 0; m >>= 1) v += __shfl_xor(v, m, 64);
  return v;
}
__device__ __forceinline__ float wredmax(float v) {
#pragma unroll
  for (int m = 32; m > 0; m >>= 1) v = fmaxf(v, __shfl_xor(v, m, 64));
  return v;
}

// ---- fast-math helpers (1-ulp HW ops + guarded series) ----
__device__ __forceinline__ float rcp_(float x) { return __builtin_amdgcn_rcpf(x); }
__device__ __forceinline__ float sqrt_(float x) { return __builtin_amdgcn_sqrtf(x); }
__device__ __forceinline__ float rsq_(float x) { return __builtin_amdgcn_rsqf(x); }
// tanh for y >= 0. Series below 0.1 (cancellation region), exp form else, 1 for y>15.
__device__ __forceinline__ float tanh_f(float y) {
  if (y > 15.f) return 1.f;
  float y2 = y * y;
  if (y < 0.1f) return y * (1.f - y2 * (1.f / 3.f) + y2 * y2 * (2.f / 15.f));
  float e = __expf(2.f * y);
  return (e - 1.f) * rcp_(e + 1.f);
}
// artanh(x)/x for 0 <= x < 1. Series below 0.1 (log((1+x)/(1-x)) rounds to 0 as x->0).
__device__ __forceinline__ float artanh_ov(float x) {
  x = fminf(x, 1.f - 1e-7f);
  float x2 = x * x;
  if (x < 0.1f) return 1.f + x2 * (1.f / 3.f) + x2 * x2 * 0.2f;
  return 0.5f * __logf((1.f + x) * rcp_(1.f - x)) * rcp_(x);
}
__device__ __forceinline__ float sigm_f(float x) { return rcp_(1.f + __expf(-x)); }
__device__ __forceinline__ float arcosh_(float x) {
  return logf(x) + log1pf(sqrtf(fmaxf(x * x - 1.f + EPSF, 0.f)) / x);
}

// ---------------- K0: pack weights + lorentz_activation(centroid) ----------------
// grid 926: blocks 0..924 pack, block 925 computes cl[201].
__global__ void k0_pack(const float* __restrict__ whh_f, const float* __restrict__ whh_b,
                        const float* __restrict__ wih_f, const float* __restrict__ wih_b,
                        const float* __restrict__ W1, const float* __restrict__ Wp,
                        const float* __restrict__ centroid,
                        float* __restrict__ wt4, float* __restrict__ wi4,
                        float* __restrict__ w1p, float* __restrict__ wp4,
                        float* __restrict__ cl) {
  __shared__ float sred[4];
  if (blockIdx.x == 925) {
    int t = threadIdx.x;
    float v = (t < 200) ? centroid[t] : 0.f;
    float ps = wred(v * v);
    if ((t & 63) == 0) sred[t >> 6] = ps;
    __syncthreads();
    float r = sqrtf(sred[0] + sred[1] + sred[2] + sred[3]);
    if (t < 200) cl[t] = v / r * sinhf(r);
    if (t == 0) cl[200] = coshf(r);
    return;
  }
  int idx = blockIdx.x * 256 + threadIdx.x;
  if (idx < 60000) {
    int kk = idx & 3; int t = idx >> 2;
    int j = t % 100; t /= 100;
    int k4 = t % 25; t /= 25;
    int g = t % 3; int dir = t / 3;
    const float* src = dir ? whh_b : whh_f;
    wt4[idx] = src[g * 10000 + j * 100 + k4 * 4 + kk];
  } else if (idx < 120000) {
    int i2 = idx - 60000;
    int kk = i2 & 3; int t = i2 >> 2;
    int c = t % 100; t /= 100;
    int k4 = t % 25; t /= 25;
    int g = t % 3; int dir = t / 3;
    const float* src = dir ? wih_b : wih_f;
    wi4[i2] = src[g * 10000 + c * 100 + k4 * 4 + kk];
  } else if (idx < 196800) {
    int i2 = idx - 120000;
    int kk = i2 & 3; int t = i2 >> 2;
    int c = t % 100; int k4 = t / 100;
    w1p[i2] = W1[c * 768 + k4 * 4 + kk];
  } else if (idx < 236800) {
    int i3 = idx - 196800;
    int kk = i3 & 3; int t = i3 >> 2;
    int c = t % 100; int t2 = t / 100;
    int k4 = t2 % 50; int ch = t2 / 50;
    wp4[i3] = Wp[(size_t)(ch * 100 + c) * 200 + k4 * 4 + kk];
  }
}

// ---------------- K1: klein(x_) @ W1^T + b1, poincare project -> p ----------------
__global__ __launch_bounds__(256, 2) void k1(const float* __restrict__ x_,
                                             const float* __restrict__ w1p,
                                             const float* __restrict__ b1,
                                             float* __restrict__ p) {
  __shared__ float4 wl[16 * 128];
  __shared__ float4 xl[64 * 16];
  __shared__ float ns[64];
  __shared__ float sscale[64];
  int t = threadIdx.x;
  int row0 = blockIdx.x * 64;
  int cg = t & 31, rg = t >> 5;
  const float4* wsrc = (const float4*)w1p;
  float nacc[4] = {0, 0, 0, 0};
  float acc[8][4] = {};
  for (int kc = 0; kc < 12; kc++) {
    int k0f4 = kc * 16;
    __syncthreads();
#pragma unroll
    for (int q = 0; q < 4; q++) {
      int idx = t + 256 * q;
      int r = idx >> 4, c4 = idx & 15;
      float4 v = *(const float4*)(x_ + (size_t)(row0 + r) * 768 + (size_t)(k0f4 + c4) * 4);
      xl[idx] = v;
      nacc[q] += v.x * v.x + v.y * v.y + v.z * v.z + v.w * v.w;
    }
#pragma unroll
    for (int q = 0; q < 8; q++) {
      int idx = t + 256 * q;
      int k4 = idx >> 7, c = idx & 127;
      float4 v = {0, 0, 0, 0};
      if (c < 100) v = wsrc[(size_t)(k0f4 + k4) * 100 + c];
      wl[idx] = v;
    }
    __syncthreads();
#pragma unroll 4
    for (int k4 = 0; k4 < 16; k4++) {
      float4 wv[4];
#pragma unroll
      for (int j = 0; j < 4; j++) wv[j] = wl[k4 * 128 + cg + 32 * j];
#pragma unroll
      for (int i = 0; i < 8; i++) {
        float4 pv = xl[(rg * 8 + i) * 16 + k4];
#pragma unroll
        for (int j = 0; j < 4; j++)
          acc[i][j] += pv.x * wv[j].x + pv.y * wv[j].y + pv.z * wv[j].z + pv.w * wv[j].w;
      }
    }
  }
  __syncthreads();
#pragma unroll
  for (int q = 0; q < 4; q++) {
    float v = nacc[q];
#pragma unroll
    for (int m = 8; m > 0; m >>= 1) v += __shfl_xor(v, m, 64);
    if ((t & 15) == 0) ns[(t >> 4) + 16 * q] = v;
  }
  __syncthreads();
  if (t < 64) {
    float rr = sqrt_(fmaxf(ns[t], MINF));
    sscale[t] = tanh_f(rr) * rcp_(rr);
  }
  __syncthreads();
  float bcol[4];
#pragma unroll
  for (int j = 0; j < 4; j++) {
    int col = cg + 32 * j;
    bcol[j] = (col < 100) ? b1[col] : 0.f;
  }
#pragma unroll
  for (int i = 0; i < 8; i++) {
    int r = rg * 8 + i;
    float s = sscale[r];
    float hv[4]; float ss = 0.f;
#pragma unroll
    for (int j = 0; j < 4; j++) {
      int col = cg + 32 * j;
      hv[j] = (col < 100) ? (s * acc[i][j] + bcol[j]) : 0.f;
      ss += hv[j] * hv[j];
    }
#pragma unroll
    for (int m = 16; m > 0; m >>= 1) ss += __shfl_xor(ss, m, 64);
    float inv = rsq_(1.f + ss);
    float* prow = p + (size_t)(row0 + r) * 100;
#pragma unroll
    for (int j = 0; j < 4; j++) {
      int col = cg + 32 * j;
      if (col < 100) prow[col] = hv[j] * inv;
    }
  }
}

// ---------------- K2: ux[combo][row] = m_matvec(Wih_combo, p[row]) ----------------
__global__ __launch_bounds__(256, 2) void k2(const float* __restrict__ p,
                                             const float* __restrict__ wi4,
                                             float* __restrict__ ux) {
  extern __shared__ float4 l4[];
  float4* wl = l4;
  float4* pl = l4 + 3200;
  float* alx = (float*)(l4 + 3200 + 64 * 26);
  int t = threadIdx.x;
  int bx = blockIdx.x;
  int combo = bx / 500, tile = bx % 500;
  int row0 = tile * 64;
  int cg = t & 31, rg = t >> 5;
  const float4* wsrc = (const float4*)wi4 + (size_t)combo * 2500;
#pragma unroll
  for (int q = 0; q < 13; q++) {
    int idx = t + 256 * q;
    if (idx < 3200) {
      int k4 = idx >> 7, c = idx & 127;
      float4 v = {0, 0, 0, 0};
      if (c < 100) v = wsrc[k4 * 100 + c];
      wl[idx] = v;
    }
  }
  const float4* psrc = (const float4*)(p + (size_t)row0 * 100);
#pragma unroll
  for (int q = 0; q < 7; q++) {
    int idx = t + 256 * q;
    if (idx < 1600) {
      int r = idx / 25, c4 = idx % 25;
      pl[r * 26 + c4] = psrc[idx];
    }
  }
  __syncthreads();
  {
    int w = t >> 6, lane = t & 63;
    const float* pf = (const float*)pl;
    for (int r = w * 16; r < w * 16 + 16; r++) {
      float v0 = pf[r * 104 + lane];
      float v1 = (lane < 36) ? pf[r * 104 + 64 + lane] : 0.f;
      float s2 = wred(v0 * v0 + v1 * v1);
      if (lane == 0) {
        float xn = sqrt_(fmaxf(s2, MINF));
        alx[r] = artanh_ov(xn);
      }
    }
  }
  __syncthreads();
  float acc[8][4] = {};
#pragma unroll 5
  for (int k4 = 0; k4 < 25; k4++) {
    float4 wv[4];
#pragma unroll
    for (int j = 0; j < 4; j++) wv[j] = wl[k4 * 128 + cg + 32 * j];
#pragma unroll
    for (int i = 0; i < 8; i++) {
      float4 pv = pl[(rg * 8 + i) * 26 + k4];
#pragma unroll
      for (int j = 0; j < 4; j++)
        acc[i][j] += pv.x * wv[j].x + pv.y * wv[j].y + pv.z * wv[j].z + pv.w * wv[j].w;
    }
  }
#pragma unroll
  for (int i = 0; i < 8; i++) {
    int r = rg * 8 + i;
    float ss = acc[i][0] * acc[i][0] + acc[i][1] * acc[i][1] +
               acc[i][2] * acc[i][2] + acc[i][3] * acc[i][3];
#pragma unroll
    for (int m = 16; m > 0; m >>= 1) ss += __shfl_xor(ss, m, 64);
    float mxn = sqrt_(fmaxf(ss, MINF));
    float sc = tanh_f(mxn * alx[r]) * rcp_(mxn);
    float* dst = ux + ((size_t)combo * 32000 + row0 + r) * 100;
#pragma unroll
    for (int j = 0; j < 4; j++) {
      int col = cg + 32 * j;
      if (col < 100) dst[col] = sc * acc[i][j];
    }
  }
}

// ---------------- K2b: per-(combo,row) |ux|^2 and <ux,bias_g> ----------------
__global__ __launch_bounds__(256) void k2b(const float* __restrict__ ux,
                                           const float* __restrict__ bias_f,
                                           const float* __restrict__ bias_b,
                                           float* __restrict__ nub) {
  int t = threadIdx.x; int w = t >> 6; int lane = t & 63;
  int gr0 = blockIdx.x * 64;
  int combo = gr0 / 32000;
  int dir = combo / 3, g = combo % 3;
  const float* bias = (dir ? bias_b : bias_f) + g * 100;
  float b0 = bias[lane];
  float b1 = (lane < 36) ? bias[64 + lane] : 0.f;
  for (int i = w * 16; i < w * 16 + 16; i++) {
    const float* u = ux + (size_t)(gr0 + i) * 100;
    float u0 = u[lane];
    float u1 = (lane < 36) ? u[64 + lane] : 0.f;
    float n2 = wred(u0 * u0 + u1 * u1);
    float ub = wred(u0 * b0 + u1 * b1);
    if (lane == 0) { nub[gr0 + i] = n2; nub[192000 + gr0 + i] = ub; }
  }
}

// ---------------- K3: sequential Mobius GRU — wave-private, barrier-free ----------------
__device__ __forceinline__ void mv100x2_reg(const float* __restrict__ Wz,
                                            const float* __restrict__ Wr,
                                            const float* __restrict__ hrow,
                                            int lane, bool hi,
                                            float& mz0, float& mz1,
                                            float& mr0, float& mr1) {
  const float4* Wz4 = (const float4*)Wz;
  const float4* Wr4 = (const float4*)Wr;
  const float4* h4 = (const float4*)hrow;
  float4 az0 = {0, 0, 0, 0}, az1 = {0, 0, 0, 0};
  float4 ar0 = {0, 0, 0, 0}, ar1 = {0, 0, 0, 0};
#pragma unroll 5
  for (int k4 = 0; k4 < 25; k4++) {
    float4 hv = h4[k4];
    float4 wz = Wz4[k4 * 100 + lane];
    float4 wr = Wr4[k4 * 100 + lane];
    az0.x += wz.x * hv.x; az0.y += wz.y * hv.y; az0.z += wz.z * hv.z; az0.w += wz.w * hv.w;
    ar0.x += wr.x * hv.x; ar0.y += wr.y * hv.y; ar0.z += wr.z * hv.z; ar0.w += wr.w * hv.w;
    if (hi) {
      float4 wzh = Wz4[k4 * 100 + 64 + lane];
      float4 wrh = Wr4[k4 * 100 + 64 + lane];
      az1.x += wzh.x * hv.x; az1.y += wzh.y * hv.y; az1.z += wzh.z * hv.z; az1.w += wzh.w * hv.w;
      ar1.x += wrh.x * hv.x; ar1.y += wrh.y * hv.y; ar1.z += wrh.z * hv.z; ar1.w += wrh.w * hv.w;
    }
  }
  mz0 = az0.x + az0.y + az0.z + az0.w;
  mr0 = ar0.x + ar0.y + ar0.z + ar0.w;
  mz1 = az1.x + az1.y + az1.z + az1.w;
  mr1 = ar1.x + ar1.y + ar1.z + ar1.w;
}

__device__ __forceinline__ void mv100_reg(const float* __restrict__ Wg,
                                          const float* __restrict__ hrow,
                                          int lane, bool hi,
                                          float& m0, float& m1) {
  const float4* W4 = (const float4*)Wg;
  const float4* h4 = (const float4*)hrow;
  float4 a0 = {0, 0, 0, 0}, a1 = {0, 0, 0, 0};
#pragma unroll 5
  for (int k4 = 0; k4 < 25; k4++) {
    float4 hv = h4[k4];
    float4 w0 = W4[k4 * 100 + lane];
    a0.x += w0.x * hv.x; a0.y += w0.y * hv.y; a0.z += w0.z * hv.z; a0.w += w0.w * hv.w;
    if (hi) {
      float4 w1 = W4[k4 * 100 + 64 + lane];
      a1.x += w1.x * hv.x; a1.y += w1.y * hv.y; a1.z += w1.z * hv.z; a1.w += w1.w * hv.w;
    }
  }
  m0 = a0.x + a0.y + a0.z + a0.w;
  m1 = a1.x + a1.y + a1.z + a1.w;
}

__device__ __forceinline__ void gate_ot(float m0, float m1, float u0, float u1,
                                        float b0v, float b1v, float C, float ub, float nb2,
                                        float alphah,
                                        float& c0, float& c1, float& Fout) {
  float A = wred(m0 * m0 + m1 * m1);
  float B = wred(m0 * u0 + m1 * u1);
  float Mb = wred(m0 * b0v + m1 * b1v);
  float mxn = sqrt_(fmaxf(A, MINF));
  float gam = tanh_f(mxn * alphah) * rcp_(mxn);
  float x2 = gam * gam * A, xy = gam * B;
  float rd = rcp_(fmaxf(1.f + 2.f * xy + x2 * C, MINF));
  float cA = (1.f + 2.f * xy + C) * gam * rd, cB = (1.f - x2) * rd;
  float D = fmaxf(cA * cA * A + 2.f * cA * cB * B + cB * cB * C, 0.f);
  float E = cA * Mb + cB * ub;
  float r2 = rcp_(fmaxf(1.f + 2.f * E + D * nb2, MINF));
  float t1 = (1.f + 2.f * E + nb2) * r2, t2 = (1.f - D) * r2;
  c0 = t1 * (cA * m0 + cB * u0) + t2 * b0v;
  c1 = t1 * (cA * m1 + cB * u1) + t2 * b1v;
  Fout = fmaxf(t1 * t1 * D + 2.f * t1 * t2 * E + t2 * t2 * nb2, MINF);
}

// grid 256 (32 groups x 8 row-chunks), block 1024 (13 live waves), LDS 131648 B.
__global__ __launch_bounds__(1024, 1) void k3(const float* __restrict__ ux,
                                              const float* __restrict__ nub,
                                              const float* __restrict__ wt4,
                                              const float* __restrict__ bias_f,
                                              const float* __restrict__ bias_b,
                                              float* __restrict__ f) {
  extern __shared__ float lds[];
  float* Wlds = lds;                 // 30000
  float* hl = lds + 30000;           // 13*112
  float* rhl = hl + 13 * 112;        // 13*112
  int t = threadIdx.x; int w = t >> 6; int lane = t & 63;
  bool hi = lane < 36;
  int bx = blockIdx.x;
  int grp = bx >> 3; int blki = bx & 7;
  int n = grp >> 1; int dir = grp & 1;
  int b0 = blki * 13; int nrows = min(13, 100 - b0);
  const float* bias = dir ? bias_b : bias_f;
  const float4* wsrc4 = (const float4*)(wt4 + dir * 30000);
  float4* Wlds4 = (float4*)Wlds;
#pragma unroll
  for (int q = 0; q < 8; q++) { int idx = t + 1024 * q; if (idx < 7500) Wlds4[idx] = wsrc4[idx]; }
  int row = w; bool erow = (w < nrows);
  if (erow) {
    hl[row * 112 + lane] = 0.f;
    if (hi) hl[row * 112 + 64 + lane] = 0.f;
  }
  __syncthreads();   // Wlds ready — the ONLY barrier in the kernel
  if (!erow) return;

  int b = b0 + row;
  float nh2 = 0.f, h0 = 0.f, h1 = 0.f;
  float br0 = bias[lane],       br1 = hi ? bias[64 + lane] : 0.f;
  float bh0 = bias[100 + lane], bh1 = hi ? bias[164 + lane] : 0.f;
  float bz0 = bias[200 + lane], bz1 = hi ? bias[264 + lane] : 0.f;
  float nbr2 = wred(br0 * br0 + br1 * br1);
  float nbh2 = wred(bh0 * bh0 + bh1 * bh1);
  float nbz2 = wred(bz0 * bz0 + bz1 * bz1);

  for (int s = 0; s < 20; s++) {
    // ---- M1: z+r matvecs on own row, results stay in registers ----
    float mz0, mz1, mr0, mr1;
    mv100x2_reg(Wlds + 2 * 10000, Wlds + 0 * 10000, hl + row * 112, lane, hi,
                mz0, mz1, mr0, mr1);
    // ---- per-step inputs ----
    int l = dir ? (1999 - (s * 100 + b)) : (s * 100 + b);
    size_t rowg = (size_t)n * 2000 + l;
    size_t iz = (size_t)(dir * 3 + 2) * 32000 + rowg;
    size_t ir = (size_t)(dir * 3 + 0) * 32000 + rowg;
    size_t ih = (size_t)(dir * 3 + 1) * 32000 + rowg;
    const float* uxz = ux + iz * 100;
    const float* uxr = ux + ir * 100;
    const float* uxhp = ux + ih * 100;
    float uz0 = uxz[lane],  uz1 = hi ? uxz[lane + 64] : 0.f;
    float ur0 = uxr[lane],  ur1 = hi ? uxr[lane + 64] : 0.f;
    float uxh0 = uxhp[lane], uxh1 = hi ? uxhp[lane + 64] : 0.f;
    float Cz = nub[iz], ubz = nub[192000 + iz];
    float Cr = nub[ir], ubr = nub[192000 + ir];
    float Ch = nub[ih], ubh = nub[192000 + ih];
    // ---- z, r gates + rh ----
    float xnh = sqrt_(fmaxf(nh2, MINF));
    float alphah = artanh_ov(xnh);
    float cz0, cz1, Fz, cr0, cr1, Fr;
    gate_ot(mz0, mz1, uz0, uz1, bz0, bz1, Cz, ubz, nbz2, alphah, cz0, cz1, Fz);
    gate_ot(mr0, mr1, ur0, ur1, br0, br1, Cr, ubr, nbr2, alphah, cr0, cr1, Fr);
    float lgz = artanh_ov(sqrt_(Fz));
    float z0 = sigm_f(lgz * cz0), z1 = sigm_f(lgz * cz1);
    float lgr = artanh_ov(sqrt_(Fr));
    float rg0 = sigm_f(lgr * cr0), rg1 = sigm_f(lgr * cr1);
    float mx0 = rg0 * h0, mx1 = rg1 * h1;
    float G = wred(mx0 * mx0 + mx1 * mx1);
    float mxnr = sqrt_(fmaxf(G, MINF));
    float srh = tanh_f(mxnr * alphah) * rcp_(mxnr);
    rhl[row * 112 + lane] = srh * mx0;
    if (hi) rhl[row * 112 + lane + 64] = srh * mx1;
    float nrh2 = srh * srh * G;
    // ---- M2: htil matvec on own row (same wave wrote rhl; no barrier) ----
    float mh0, mh1;
    mv100_reg(Wlds + 1 * 10000, rhl + row * 112, lane, hi, mh0, mh1);
    // ---- htil, d, pw, hn ----
    float xnrh = sqrt_(fmaxf(nrh2, MINF));
    float alpharh = artanh_ov(xnrh);
    float ct0, ct1, T;
    gate_ot(mh0, mh1, uxh0, uxh1, bh0, bh1, Ch, ubh, nbh2, alpharh, ct0, ct1, T);
    float U = wred(h0 * ct0 + h1 * ct1);
    float rdd = rcp_(fmaxf(1.f - 2.f * U + nh2 * T, MINF));
    float cAd = (1.f - 2.f * U + T) * rdd, cBd = (1.f - nh2) * rdd;
    float d0 = -cAd * h0 + cBd * ct0, d1 = -cAd * h1 + cBd * ct1;
    float nd2 = fmaxf(cAd * cAd * nh2 - 2.f * cAd * cBd * U + cBd * cBd * T, MINF);
    float zd0 = z0 * d0, zd1 = z1 * d1;
    float P = wred(zd0 * zd0 + zd1 * zd1);
    float Q = wred(h0 * zd0 + h1 * zd1);
    float xnd = sqrt_(nd2);
    float mxnp = sqrt_(fmaxf(P, MINF));
    float sp = tanh_f(mxnp * artanh_ov(xnd)) * rcp_(mxnp);
    float y2p = sp * sp * P, xyp = sp * Q;
    float r3 = rcp_(fmaxf(1.f + 2.f * xyp + nh2 * y2p, MINF));
    float A1 = (1.f + 2.f * xyp + y2p) * r3, B1 = (1.f - nh2) * r3 * sp;
    float hn0 = A1 * h0 + B1 * zd0, hn1 = A1 * h1 + B1 * zd1;
    nh2 = fmaxf(A1 * A1 * nh2 + 2.f * A1 * B1 * Q + B1 * B1 * P, 0.f);
    h0 = hn0; h1 = hn1;
    hl[row * 112 + lane] = hn0;
    if (hi) hl[row * 112 + lane + 64] = hn1;
    float* fd = f + (((size_t)n * 20 + s) * 100 + b) * 200 + dir * 100;
    fd[lane] = hn0;
    if (hi) fd[lane + 64] = hn1;
  }
}

// ---------------- K4ag: mx = f @ Wp^T (raw), register-tiled ----------------
__global__ __launch_bounds__(256, 2) void k4ag(const float* __restrict__ f,
                                               const float* __restrict__ wp4,
                                               float* __restrict__ mx) {
  extern __shared__ float4 g4[];
  float4* wl = g4;
  float4* pl = g4 + 3200;
  int t = threadIdx.x;
  int bx = blockIdx.x;
  int ch = bx & 1, tile = bx >> 1;
  int row0 = tile * 64;
  int cg = t & 31, rg = t >> 5;
  const float4* wsrc = (const float4*)wp4 + (size_t)ch * 5000;
  const float4* psrc = (const float4*)(f + (size_t)row0 * 200);
  float acc[8][4] = {};
  for (int kc = 0; kc < 2; kc++) {
    __syncthreads();
#pragma unroll
    for (int q = 0; q < 13; q++) {
      int idx = t + 256 * q;
      if (idx < 3200) {
        int k4 = idx >> 7, c = idx & 127;
        float4 v = {0, 0, 0, 0};
        if (c < 100) v = wsrc[(kc * 25 + k4) * 100 + c];
        wl[idx] = v;
      }
    }
#pragma unroll
    for (int q = 0; q < 7; q++) {
      int idx = t + 256 * q;
      if (idx < 1600) {
        int r = idx / 25, k4 = idx % 25;
        pl[r * 26 + k4] = psrc[r * 50 + kc * 25 + k4];
      }
    }
    __syncthreads();
#pragma unroll 5
    for (int k4 = 0; k4 < 25; k4++) {
      float4 wv[4];
#pragma unroll
      for (int j = 0; j < 4; j++) wv[j] = wl[k4 * 128 + cg + 32 * j];
#pragma unroll
      for (int i = 0; i < 8; i++) {
        float4 pv = pl[(rg * 8 + i) * 26 + k4];
#pragma unroll
        for (int j = 0; j < 4; j++)
          acc[i][j] += pv.x * wv[j].x + pv.y * wv[j].y + pv.z * wv[j].z + pv.w * wv[j].w;
      }
    }
  }
#pragma unroll
  for (int i = 0; i < 8; i++) {
    float* dst = mx + (size_t)(row0 + rg * 8 + i) * 200 + ch * 100;
#pragma unroll
    for (int j = 0; j < 4; j++) {
      int col = cg + 32 * j;
      if (col < 100) dst[col] = acc[i][j];
    }
  }
}

// ---------------- K4ae: Mobius m_add(bp) + lorentz logits a, gamma ----------------
__global__ __launch_bounds__(256) void k4ae(const float* __restrict__ f,
                                            const float* __restrict__ mx,
                                            const float* __restrict__ bp,
                                            const float* __restrict__ cl,
                                            const float* __restrict__ beta_p,
                                            float* __restrict__ a_out, float* __restrict__ g_out) {
  int t = threadIdx.x; int w = t >> 6; int lane = t & 63;
  int row0 = blockIdx.x * 64;
  float beta = beta_p[0];
  float c200 = cl[200];
  float b_0 = bp[lane], b_1 = bp[lane + 64], b_2 = bp[lane + 128];
  float b_3 = (lane < 8) ? bp[lane + 192] : 0.f;
  float c_0 = cl[lane], c_1 = cl[lane + 64], c_2 = cl[lane + 128];
  float c_3 = (lane < 8) ? cl[lane + 192] : 0.f;
  float nbp2 = wred(b_0 * b_0 + b_1 * b_1 + b_2 * b_2 + b_3 * b_3);
  for (int r = w * 16; r < w * 16 + 16; r++) {
    const float* fr = f + (size_t)(row0 + r) * 200;
    const float* mr = mx + (size_t)(row0 + r) * 200;
    float f0 = fr[lane], f1 = fr[lane + 64], f2 = fr[lane + 128];
    float f3 = (lane < 8) ? fr[lane + 192] : 0.f;
    float nf2 = wred(f0 * f0 + f1 * f1 + f2 * f2 + f3 * f3);
    float xn = sqrt_(fmaxf(nf2, MINF));
    float alx = artanh_ov(xn);
    float m0 = mr[lane], m1 = mr[lane + 64], m2 = mr[lane + 128];
    float m3 = (lane < 8) ? mr[lane + 192] : 0.f;
    float A = wred(m0 * m0 + m1 * m1 + m2 * m2 + m3 * m3);
    float B = wred(m0 * b_0 + m1 * b_1 + m2 * b_2 + m3 * b_3);
    float mxn = sqrt_(fmaxf(A, MINF));
    float gam = tanh_f(mxn * alx) * rcp_(mxn);
    float x2 = gam * gam * A, y2 = nbp2, xy = gam * B;
    float rd = rcp_(fmaxf(1.f + 2.f * xy + x2 * y2, MINF));
    float cA = (1.f + 2.f * xy + y2) * gam * rd, cB = (1.f - x2) * rd;
    float a0 = cA * m0 + cB * b_0, a1 = cA * m1 + cB * b_1;
    float a2 = cA * m2 + cB * b_2, a3 = cA * m3 + cB * b_3;
    float r2 = wred(a0 * a0 + a1 * a1 + a2 * a2 + a3 * a3);
    float dc = wred(a0 * c_0 + a1 * c_1 + a2 * c_2 + a3 * c_3);
    float pm = (-2.f * dc + (1.f + r2) * c200) / (1.f - r2 + EPSF);
    pm = fminf(fmaxf(pm, 1.f + EPSF), 1e16f);
    float av = -beta * arcosh_(pm) - 1.f;
    float invg = 1.f - 4.f * nf2 / ((1.f + nf2) * (1.f + nf2));
    invg = fminf(fmaxf(invg, EPSF), 1.f - EPSF);
    float gv = fminf(fmaxf(rsq_(invg), 1.f + EPSF), 1e16f);
    if (lane == 0) { a_out[row0 + r] = av; g_out[row0 + r] = gv; }
  }
}

// ---------------- K4b: per-sample softmax weights ----------------
__global__ __launch_bounds__(256) void k4b(const float* __restrict__ a_in,
                                           const float* __restrict__ g_in,
                                           float* __restrict__ wgt) {
  __shared__ float rl[2000];
  __shared__ float sred[4];
  __shared__ float rsinv[100];
  int n = blockIdx.x; int t = threadIdx.x;
  int w = t >> 6, lane = t & 63;
  const float* ap = a_in + n * 2000;
  const float* gp = g_in + n * 2000;
  float av[8]; float am = -1e30f;
#pragma unroll
  for (int q = 0; q < 8; q++) {
    int i = t + 256 * q;
    av[q] = (i < 2000) ? ap[i] : -1e30f;
    am = fmaxf(am, av[q]);
  }
  am = wredmax(am);
  if (lane == 0) sred[w] = am;
  __syncthreads();
  float amax = fmaxf(fmaxf(sred[0], sred[1]), fmaxf(sred[2], sred[3]));
#pragma unroll
  for (int q = 0; q < 8; q++) {
    int i = t + 256 * q;
    if (i < 2000) rl[i] = expf(av[q] - amax) * gp[i];
  }
  __syncthreads();
  if (t < 100) {
    float ssum = 0.f;
#pragma unroll
    for (int s = 0; s < 20; s++) ssum += rl[s * 100 + t];
    rsinv[t] = 1.f / ssum;
  }
  __syncthreads();
#pragma unroll
  for (int q = 0; q < 8; q++) {
    int i = t + 256 * q;
    if (i < 2000) wgt[n * 2000 + i] = rl[i] * rsinv[i % 100];
  }
}

// ---------------- K4c: klein aggregation + final GEMM W2 ----------------
// o-accumulation parallelized across 4 waves (was 100 serial loads on 200 threads).
__global__ __launch_bounds__(256) void k4c(const float* __restrict__ f, const float* __restrict__ wgt,
                                           const float* __restrict__ W2, const float* __restrict__ b2,
                                           float* __restrict__ out) {
  __shared__ float cw[100];
  __shared__ float part[4][204];
  __shared__ float ol[200];
  __shared__ float sred[4];
  int bx = blockIdx.x; int n = bx / 20, s = bx % 20;
  int t = threadIdx.x; int w = t >> 6; int lane = t & 63;
  const float* fb = f + ((size_t)n * 20 + s) * 100 * 200;
  for (int bi = w * 25; bi < w * 25 + 25; bi++) {
    const float* fr = fb + bi * 200;
    float v0 = fr[lane], v1 = fr[lane + 64], v2 = fr[lane + 128];
    float v3 = (lane < 8) ? fr[lane + 192] : 0.f;
    float s2 = wred(v0 * v0 + v1 * v1 + v2 * v2 + v3 * v3);
    if (lane == 0) cw[bi] = wgt[n * 2000 + s * 100 + bi] * 2.f * rcp_(1.f + s2);
  }
  __syncthreads();
  float o0 = 0, o1 = 0, o2 = 0, o3 = 0;
  for (int bi = w * 25; bi < w * 25 + 25; bi++) {
    float c = cw[bi];
    const float* fr = fb + bi * 200;
    o0 += c * fr[lane]; o1 += c * fr[lane + 64]; o2 += c * fr[lane + 128];
    if (lane < 8) o3 += c * fr[lane + 192];
  }
  part[w][lane] = o0; part[w][lane + 64] = o1; part[w][lane + 128] = o2;
  if (lane < 8) part[w][lane + 192] = o3;
  __syncthreads();
  float o = 0.f;
  if (t < 200) o = part[0][t] + part[1][t] + part[2][t] + part[3][t];
  float ps = (t < 200) ? o * o : 0.f;
  ps = wred(ps);
  if (lane == 0) sred[w] = ps;
  __syncthreads();
  float no2 = sred[0] + sred[1] + sred[2] + sred[3];
  float denom = 1.f + sqrtf(1.f + no2);
  if (t < 200) ol[t] = o / denom;
  __syncthreads();
  const float4* ol4 = (const float4*)ol;
#pragma unroll
  for (int jj = 0; jj < 3; jj++) {
    int j = t + 256 * jj;
    const float4* wrow = (const float4*)(W2 + (size_t)j * 200);
    float a0 = 0, a1 = 0, a2 = 0, a3 = 0;
    for (int k4 = 0; k4 < 50; k4++) {
      float4 wv = wrow[k4]; float4 ov = ol4[k4];
      a0 += wv.x * ov.x; a1 += wv.y * ov.y; a2 += wv.z * ov.z; a3 += wv.w * ov.w;
    }
    out[((size_t)n * 20 + s) * 768 + j] = a0 + a1 + a2 + a3 + b2[j];
  }
}

extern "C" void kernel_launch(void* const* d_in, const int* in_sizes, int n_in,
                              void* d_out, int out_size, void* d_ws, size_t ws_size,
                              hipStream_t stream) {
  const float* x_     = (const float*)d_in[0];
  const float* W1     = (const float*)d_in[1];
  const float* b1     = (const float*)d_in[2];
  const float* W2     = (const float*)d_in[3];
  const float* b2     = (const float*)d_in[4];
  const float* Wih_f  = (const float*)d_in[5];
  const float* Whh_f  = (const float*)d_in[6];
  const float* bias_f = (const float*)d_in[7];
  const float* Wih_b  = (const float*)d_in[8];
  const float* Whh_b  = (const float*)d_in[9];
  const float* bias_b = (const float*)d_in[10];
  const float* centroid = (const float*)d_in[11];
  const float* Wp     = (const float*)d_in[12];
  const float* bp     = (const float*)d_in[13];
  const float* beta   = (const float*)d_in[14];
  float* out = (float*)d_out;
  float* ws = (float*)d_ws;
  float* p   = ws + OFF_P;
  float* ux  = ws + OFF_UX;
  float* wt4 = ws + OFF_WT4;
  float* f   = ws + OFF_F;
  float* wi4 = ws + OFF_WI4;
  float* w1p = ws + OFF_W1P;
  float* mx  = ws + OFF_MX;
  float* wp4 = ws + OFF_WP4;
  float* nub = ws + OFF_NUB;
  float* cl  = ws + OFF_CL;
  float* aa  = ws + OFF_A;
  float* gg  = ws + OFF_G;
  float* wg  = ws + OFF_WGT;

  (void)hipFuncSetAttribute(reinterpret_cast<const void*>(k3),
                            hipFuncAttributeMaxDynamicSharedMemorySize, K3_LDS_BYTES);
  (void)hipFuncSetAttribute(reinterpret_cast<const void*>(k2),
                            hipFuncAttributeMaxDynamicSharedMemorySize, K2_LDS_BYTES);
  (void)hipFuncSetAttribute(reinterpret_cast<const void*>(k4ag),
                            hipFuncAttributeMaxDynamicSharedMemorySize, K4G_LDS_BYTES);

  k0_pack<<<926, 256, 0, stream>>>(Whh_f, Whh_b, Wih_f, Wih_b, W1, Wp, centroid,
                                   wt4, wi4, w1p, wp4, cl);
  k1<<<500, 256, 0, stream>>>(x_, w1p, b1, p);
  k2<<<3000, 256, K2_LDS_BYTES, stream>>>(p, wi4, ux);
  k2b<<<3000, 256, 0, stream>>>(ux, bias_f, bias_b, nub);
  k3<<<256, 1024, K3_LDS_BYTES, stream>>>(ux, nub, wt4, bias_f, bias_b, f);
  k4ag<<<1000, 256, K4G_LDS_BYTES, stream>>>(f, wp4, mx);
  k4ae<<<500, 256, 0, stream>>>(f, mx, bp, cl, beta, aa, gg);
  k4b<<<16, 256, 0, stream>>>(aa, gg, wg);
  k4c<<<320, 256, 0, stream>>>(f, wg, W2, b2, out);
}

// Round 8
// 728.315 us; speedup vs baseline: 2.4428x; 1.0751x over previous
//
#include <hip/hip_runtime.h>
#include <hip/hip_bf16.h>

#define MINF 1e-15f
#define EPSF 1e-6f

// ---------- workspace layout (floats) ----------
#define OFF_P    0u            // 16*2000*100      = 3,200,000
#define OFF_UX   3200000u      // 2*3*32000*100    = 19,200,000
#define OFF_WT4  22400000u     // 2*3*25*100*4     = 60,000
#define OFF_F    22460000u     // 16*20*100*200    = 6,400,000
#define OFF_CL   28860000u     // 206 used (pad 256)
#define OFF_A    28860256u     // 32000
#define OFF_G    28892256u     // 32000
#define OFF_WGT  28924256u     // 32000
#define OFF_NUBT 28956256u     // 384,000 nub tail (used if ws_size allows)
#define OFF_WI4  OFF_F
#define OFF_W1P  (OFF_F + 60000u)
#define OFF_WP4  OFF_A
// k4 row-scalar partials reuse the ux region (dead after k3):
//   Ah[2][32000] Bh[2][32000] Mh[2][32000] nf2[32000] at OFF_UX.

#define K3_LDS_BYTES ((30000 + 2*13*112) * 4)     // W 120000 + hl/rhl 11648 = 131648
#define K2_LDS_BYTES ((3200 + 64*26)*16 + 64*4)   // W 51200 + p 26624 + alx 256 = 78080
#define K4G_LDS_BYTES ((3200 + 64*26)*16)         // W 51200 + f 26624 = 77824

__device__ __forceinline__ float wred(float v) {
#pragma unroll
  for (int m = 32; m > 0; m >>= 1) v += __shfl_xor(v, m, 64);
  return v;
}
__device__ __forceinline__ float wredmax(float v) {
#pragma unroll
  for (int m = 32; m > 0; m >>= 1) v = fmaxf(v, __shfl_xor(v, m, 64));
  return v;
}

// ---- fast-math helpers (1-ulp HW ops + guarded series) ----
__device__ __forceinline__ float rcp_(float x) { return __builtin_amdgcn_rcpf(x); }
__device__ __forceinline__ float sqrt_(float x) { return __builtin_amdgcn_sqrtf(x); }
__device__ __forceinline__ float rsq_(float x) { return __builtin_amdgcn_rsqf(x); }
__device__ __forceinline__ float tanh_f(float y) {
  if (y > 15.f) return 1.f;
  float y2 = y * y;
  if (y < 0.1f) return y * (1.f - y2 * (1.f / 3.f) + y2 * y2 * (2.f / 15.f));
  float e = __expf(2.f * y);
  return (e - 1.f) * rcp_(e + 1.f);
}
__device__ __forceinline__ float artanh_ov(float x) {
  x = fminf(x, 1.f - 1e-7f);
  float x2 = x * x;
  if (x < 0.1f) return 1.f + x2 * (1.f / 3.f) + x2 * x2 * 0.2f;
  return 0.5f * __logf((1.f + x) * rcp_(1.f - x)) * rcp_(x);
}
__device__ __forceinline__ float sigm_f(float x) { return rcp_(1.f + __expf(-x)); }
__device__ __forceinline__ float arcosh_(float x) {
  return logf(x) + log1pf(sqrtf(fmaxf(x * x - 1.f + EPSF, 0.f)) / x);
}

// ---------------- K0: pack weights + centroid/bp constants ----------------
// grid 926: blocks 0..924 pack, block 925 computes cl[0..200], cl[204]=|bp|^2,
// cl[205]=<bp,cl>.
__global__ void k0_pack(const float* __restrict__ whh_f, const float* __restrict__ whh_b,
                        const float* __restrict__ wih_f, const float* __restrict__ wih_b,
                        const float* __restrict__ W1, const float* __restrict__ Wp,
                        const float* __restrict__ centroid, const float* __restrict__ bp,
                        float* __restrict__ wt4, float* __restrict__ wi4,
                        float* __restrict__ w1p, float* __restrict__ wp4,
                        float* __restrict__ cl) {
  __shared__ float sr1[4], sr2[4], sr3[4];
  if (blockIdx.x == 925) {
    int t = threadIdx.x; int w = t >> 6, lane = t & 63;
    float v = (t < 200) ? centroid[t] : 0.f;
    float ps = wred(v * v);
    if (lane == 0) sr1[w] = ps;
    __syncthreads();
    float r = sqrtf(sr1[0] + sr1[1] + sr1[2] + sr1[3]);
    float clv = (t < 200) ? (v / r * sinhf(r)) : 0.f;
    if (t < 200) cl[t] = clv;
    if (t == 0) cl[200] = coshf(r);
    float bv = (t < 200) ? bp[t] : 0.f;
    float p2 = wred(bv * bv);
    float p3 = wred(bv * clv);
    if (lane == 0) { sr2[w] = p2; sr3[w] = p3; }
    __syncthreads();
    if (t == 0) {
      cl[204] = sr2[0] + sr2[1] + sr2[2] + sr2[3];
      cl[205] = sr3[0] + sr3[1] + sr3[2] + sr3[3];
    }
    return;
  }
  int idx = blockIdx.x * 256 + threadIdx.x;
  if (idx < 60000) {
    int kk = idx & 3; int t = idx >> 2;
    int j = t % 100; t /= 100;
    int k4 = t % 25; t /= 25;
    int g = t % 3; int dir = t / 3;
    const float* src = dir ? whh_b : whh_f;
    wt4[idx] = src[g * 10000 + j * 100 + k4 * 4 + kk];
  } else if (idx < 120000) {
    int i2 = idx - 60000;
    int kk = i2 & 3; int t = i2 >> 2;
    int c = t % 100; t /= 100;
    int k4 = t % 25; t /= 25;
    int g = t % 3; int dir = t / 3;
    const float* src = dir ? wih_b : wih_f;
    wi4[i2] = src[g * 10000 + c * 100 + k4 * 4 + kk];
  } else if (idx < 196800) {
    int i2 = idx - 120000;
    int kk = i2 & 3; int t = i2 >> 2;
    int c = t % 100; int k4 = t / 100;
    w1p[i2] = W1[c * 768 + k4 * 4 + kk];
  } else if (idx < 236800) {
    int i3 = idx - 196800;
    int kk = i3 & 3; int t = i3 >> 2;
    int c = t % 100; int t2 = t / 100;
    int k4 = t2 % 50; int ch = t2 / 50;
    wp4[i3] = Wp[(size_t)(ch * 100 + c) * 200 + k4 * 4 + kk];
  }
}

// ---------------- K1: klein(x_) @ W1^T + b1, poincare project -> p ----------------
__global__ __launch_bounds__(256, 2) void k1(const float* __restrict__ x_,
                                             const float* __restrict__ w1p,
                                             const float* __restrict__ b1,
                                             float* __restrict__ p) {
  __shared__ float4 wl[16 * 128];
  __shared__ float4 xl[64 * 16];
  __shared__ float ns[64];
  __shared__ float sscale[64];
  int t = threadIdx.x;
  int row0 = blockIdx.x * 64;
  int cg = t & 31, rg = t >> 5;
  const float4* wsrc = (const float4*)w1p;
  float nacc[4] = {0, 0, 0, 0};
  float acc[8][4] = {};
  for (int kc = 0; kc < 12; kc++) {
    int k0f4 = kc * 16;
    __syncthreads();
#pragma unroll
    for (int q = 0; q < 4; q++) {
      int idx = t + 256 * q;
      int r = idx >> 4, c4 = idx & 15;
      float4 v = *(const float4*)(x_ + (size_t)(row0 + r) * 768 + (size_t)(k0f4 + c4) * 4);
      xl[idx] = v;
      nacc[q] += v.x * v.x + v.y * v.y + v.z * v.z + v.w * v.w;
    }
#pragma unroll
    for (int q = 0; q < 8; q++) {
      int idx = t + 256 * q;
      int k4 = idx >> 7, c = idx & 127;
      float4 v = {0, 0, 0, 0};
      if (c < 100) v = wsrc[(size_t)(k0f4 + k4) * 100 + c];
      wl[idx] = v;
    }
    __syncthreads();
#pragma unroll 4
    for (int k4 = 0; k4 < 16; k4++) {
      float4 wv[4];
#pragma unroll
      for (int j = 0; j < 4; j++) wv[j] = wl[k4 * 128 + cg + 32 * j];
#pragma unroll
      for (int i = 0; i < 8; i++) {
        float4 pv = xl[(rg * 8 + i) * 16 + k4];
#pragma unroll
        for (int j = 0; j < 4; j++)
          acc[i][j] += pv.x * wv[j].x + pv.y * wv[j].y + pv.z * wv[j].z + pv.w * wv[j].w;
      }
    }
  }
  __syncthreads();
#pragma unroll
  for (int q = 0; q < 4; q++) {
    float v = nacc[q];
#pragma unroll
    for (int m = 8; m > 0; m >>= 1) v += __shfl_xor(v, m, 64);
    if ((t & 15) == 0) ns[(t >> 4) + 16 * q] = v;
  }
  __syncthreads();
  if (t < 64) {
    float rr = sqrt_(fmaxf(ns[t], MINF));
    sscale[t] = tanh_f(rr) * rcp_(rr);
  }
  __syncthreads();
  float bcol[4];
#pragma unroll
  for (int j = 0; j < 4; j++) {
    int col = cg + 32 * j;
    bcol[j] = (col < 100) ? b1[col] : 0.f;
  }
#pragma unroll
  for (int i = 0; i < 8; i++) {
    int r = rg * 8 + i;
    float s = sscale[r];
    float hv[4]; float ss = 0.f;
#pragma unroll
    for (int j = 0; j < 4; j++) {
      int col = cg + 32 * j;
      hv[j] = (col < 100) ? (s * acc[i][j] + bcol[j]) : 0.f;
      ss += hv[j] * hv[j];
    }
#pragma unroll
    for (int m = 16; m > 0; m >>= 1) ss += __shfl_xor(ss, m, 64);
    float inv = rsq_(1.f + ss);
    float* prow = p + (size_t)(row0 + r) * 100;
#pragma unroll
    for (int j = 0; j < 4; j++) {
      int col = cg + 32 * j;
      if (col < 100) prow[col] = hv[j] * inv;
    }
  }
}

// ---------------- K2: ux + (optionally fused) nub ----------------
template <bool DO_NUB>
__global__ __launch_bounds__(256, 2) void k2t(const float* __restrict__ p,
                                              const float* __restrict__ wi4,
                                              const float* __restrict__ bias_f,
                                              const float* __restrict__ bias_b,
                                              float* __restrict__ ux,
                                              float* __restrict__ nub) {
  extern __shared__ float4 l4[];
  float4* wl = l4;
  float4* pl = l4 + 3200;
  float* alx = (float*)(l4 + 3200 + 64 * 26);
  int t = threadIdx.x;
  int bx = blockIdx.x;
  int combo = bx / 500, tile = bx % 500;
  int row0 = tile * 64;
  int cg = t & 31, rg = t >> 5;
  const float4* wsrc = (const float4*)wi4 + (size_t)combo * 2500;
#pragma unroll
  for (int q = 0; q < 13; q++) {
    int idx = t + 256 * q;
    if (idx < 3200) {
      int k4 = idx >> 7, c = idx & 127;
      float4 v = {0, 0, 0, 0};
      if (c < 100) v = wsrc[k4 * 100 + c];
      wl[idx] = v;
    }
  }
  const float4* psrc = (const float4*)(p + (size_t)row0 * 100);
#pragma unroll
  for (int q = 0; q < 7; q++) {
    int idx = t + 256 * q;
    if (idx < 1600) {
      int r = idx / 25, c4 = idx % 25;
      pl[r * 26 + c4] = psrc[idx];
    }
  }
  __syncthreads();
  {
    int w = t >> 6, lane = t & 63;
    const float* pf = (const float*)pl;
    for (int r = w * 16; r < w * 16 + 16; r++) {
      float v0 = pf[r * 104 + lane];
      float v1 = (lane < 36) ? pf[r * 104 + 64 + lane] : 0.f;
      float s2 = wred(v0 * v0 + v1 * v1);
      if (lane == 0) {
        float xn = sqrt_(fmaxf(s2, MINF));
        alx[r] = artanh_ov(xn);
      }
    }
  }
  __syncthreads();
  float acc[8][4] = {};
#pragma unroll 5
  for (int k4 = 0; k4 < 25; k4++) {
    float4 wv[4];
#pragma unroll
    for (int j = 0; j < 4; j++) wv[j] = wl[k4 * 128 + cg + 32 * j];
#pragma unroll
    for (int i = 0; i < 8; i++) {
      float4 pv = pl[(rg * 8 + i) * 26 + k4];
#pragma unroll
      for (int j = 0; j < 4; j++)
        acc[i][j] += pv.x * wv[j].x + pv.y * wv[j].y + pv.z * wv[j].z + pv.w * wv[j].w;
    }
  }
  float bcol[4] = {0, 0, 0, 0};
  if (DO_NUB) {
    int dir = combo / 3, g = combo % 3;
    const float* bias = (dir ? bias_b : bias_f) + g * 100;
#pragma unroll
    for (int j = 0; j < 4; j++) {
      int col = cg + 32 * j;
      bcol[j] = (col < 100) ? bias[col] : 0.f;
    }
  }
#pragma unroll
  for (int i = 0; i < 8; i++) {
    int r = rg * 8 + i;
    float ss = acc[i][0] * acc[i][0] + acc[i][1] * acc[i][1] +
               acc[i][2] * acc[i][2] + acc[i][3] * acc[i][3];
    float ub = 0.f;
    if (DO_NUB)
      ub = acc[i][0] * bcol[0] + acc[i][1] * bcol[1] +
           acc[i][2] * bcol[2] + acc[i][3] * bcol[3];
#pragma unroll
    for (int m = 16; m > 0; m >>= 1) {
      ss += __shfl_xor(ss, m, 64);
      if (DO_NUB) ub += __shfl_xor(ub, m, 64);
    }
    float mxn = sqrt_(fmaxf(ss, MINF));
    float sc = tanh_f(mxn * alx[r]) * rcp_(mxn);
    if (DO_NUB && cg == 0) {
      size_t gi = (size_t)combo * 32000 + row0 + r;
      nub[gi] = sc * sc * ss;            // |ux|^2
      nub[192000 + gi] = sc * ub;        // <ux, bias_g>
    }
    float* dst = ux + ((size_t)combo * 32000 + row0 + r) * 100;
#pragma unroll
    for (int j = 0; j < 4; j++) {
      int col = cg + 32 * j;
      if (col < 100) dst[col] = sc * acc[i][j];
    }
  }
}

// ---------------- K2b: fallback nub pass (only if ws too small to fuse) ----------------
__global__ __launch_bounds__(256) void k2b(const float* __restrict__ ux,
                                           const float* __restrict__ bias_f,
                                           const float* __restrict__ bias_b,
                                           float* __restrict__ nub) {
  int t = threadIdx.x; int w = t >> 6; int lane = t & 63;
  int gr0 = blockIdx.x * 64;
  int combo = gr0 / 32000;
  int dir = combo / 3, g = combo % 3;
  const float* bias = (dir ? bias_b : bias_f) + g * 100;
  float b0 = bias[lane];
  float b1 = (lane < 36) ? bias[64 + lane] : 0.f;
  for (int i = w * 16; i < w * 16 + 16; i++) {
    const float* u = ux + (size_t)(gr0 + i) * 100;
    float u0 = u[lane];
    float u1 = (lane < 36) ? u[64 + lane] : 0.f;
    float n2 = wred(u0 * u0 + u1 * u1);
    float ub = wred(u0 * b0 + u1 * b1);
    if (lane == 0) { nub[gr0 + i] = n2; nub[192000 + gr0 + i] = ub; }
  }
}

// ---------------- K3: sequential Mobius GRU — wave-private, barrier-free ----------------
__device__ __forceinline__ void mv100x2_reg(const float* __restrict__ Wz,
                                            const float* __restrict__ Wr,
                                            const float* __restrict__ hrow,
                                            int lane, bool hi,
                                            float& mz0, float& mz1,
                                            float& mr0, float& mr1) {
  const float4* Wz4 = (const float4*)Wz;
  const float4* Wr4 = (const float4*)Wr;
  const float4* h4 = (const float4*)hrow;
  float4 az0 = {0, 0, 0, 0}, az1 = {0, 0, 0, 0};
  float4 ar0 = {0, 0, 0, 0}, ar1 = {0, 0, 0, 0};
#pragma unroll 5
  for (int k4 = 0; k4 < 25; k4++) {
    float4 hv = h4[k4];
    float4 wz = Wz4[k4 * 100 + lane];
    float4 wr = Wr4[k4 * 100 + lane];
    az0.x += wz.x * hv.x; az0.y += wz.y * hv.y; az0.z += wz.z * hv.z; az0.w += wz.w * hv.w;
    ar0.x += wr.x * hv.x; ar0.y += wr.y * hv.y; ar0.z += wr.z * hv.z; ar0.w += wr.w * hv.w;
    if (hi) {
      float4 wzh = Wz4[k4 * 100 + 64 + lane];
      float4 wrh = Wr4[k4 * 100 + 64 + lane];
      az1.x += wzh.x * hv.x; az1.y += wzh.y * hv.y; az1.z += wzh.z * hv.z; az1.w += wzh.w * hv.w;
      ar1.x += wrh.x * hv.x; ar1.y += wrh.y * hv.y; ar1.z += wrh.z * hv.z; ar1.w += wrh.w * hv.w;
    }
  }
  mz0 = az0.x + az0.y + az0.z + az0.w;
  mr0 = ar0.x + ar0.y + ar0.z + ar0.w;
  mz1 = az1.x + az1.y + az1.z + az1.w;
  mr1 = ar1.x + ar1.y + ar1.z + ar1.w;
}

__device__ __forceinline__ void mv100_reg(const float* __restrict__ Wg,
                                          const float* __restrict__ hrow,
                                          int lane, bool hi,
                                          float& m0, float& m1) {
  const float4* W4 = (const float4*)Wg;
  const float4* h4 = (const float4*)hrow;
  float4 a0 = {0, 0, 0, 0}, a1 = {0, 0, 0, 0};
#pragma unroll 5
  for (int k4 = 0; k4 < 25; k4++) {
    float4 hv = h4[k4];
    float4 w0 = W4[k4 * 100 + lane];
    a0.x += w0.x * hv.x; a0.y += w0.y * hv.y; a0.z += w0.z * hv.z; a0.w += w0.w * hv.w;
    if (hi) {
      float4 w1 = W4[k4 * 100 + 64 + lane];
      a1.x += w1.x * hv.x; a1.y += w1.y * hv.y; a1.z += w1.z * hv.z; a1.w += w1.w * hv.w;
    }
  }
  m0 = a0.x + a0.y + a0.z + a0.w;
  m1 = a1.x + a1.y + a1.z + a1.w;
}

__device__ __forceinline__ void gate_ot(float m0, float m1, float u0, float u1,
                                        float b0v, float b1v, float C, float ub, float nb2,
                                        float alphah,
                                        float& c0, float& c1, float& Fout) {
  float A = wred(m0 * m0 + m1 * m1);
  float B = wred(m0 * u0 + m1 * u1);
  float Mb = wred(m0 * b0v + m1 * b1v);
  float mxn = sqrt_(fmaxf(A, MINF));
  float gam = tanh_f(mxn * alphah) * rcp_(mxn);
  float x2 = gam * gam * A, xy = gam * B;
  float rd = rcp_(fmaxf(1.f + 2.f * xy + x2 * C, MINF));
  float cA = (1.f + 2.f * xy + C) * gam * rd, cB = (1.f - x2) * rd;
  float D = fmaxf(cA * cA * A + 2.f * cA * cB * B + cB * cB * C, 0.f);
  float E = cA * Mb + cB * ub;
  float r2 = rcp_(fmaxf(1.f + 2.f * E + D * nb2, MINF));
  float t1 = (1.f + 2.f * E + nb2) * r2, t2 = (1.f - D) * r2;
  c0 = t1 * (cA * m0 + cB * u0) + t2 * b0v;
  c1 = t1 * (cA * m1 + cB * u1) + t2 * b1v;
  Fout = fmaxf(t1 * t1 * D + 2.f * t1 * t2 * E + t2 * t2 * nb2, MINF);
}

// grid 256 (32 groups x 8 row-chunks), block 1024 (13 live waves), LDS 131648 B.
__global__ __launch_bounds__(1024, 1) void k3(const float* __restrict__ ux,
                                              const float* __restrict__ nub,
                                              const float* __restrict__ wt4,
                                              const float* __restrict__ bias_f,
                                              const float* __restrict__ bias_b,
                                              float* __restrict__ f) {
  extern __shared__ float lds[];
  float* Wlds = lds;                 // 30000
  float* hl = lds + 30000;           // 13*112
  float* rhl = hl + 13 * 112;        // 13*112
  int t = threadIdx.x; int w = t >> 6; int lane = t & 63;
  bool hi = lane < 36;
  int bx = blockIdx.x;
  int grp = bx >> 3; int blki = bx & 7;
  int n = grp >> 1; int dir = grp & 1;
  int b0 = blki * 13; int nrows = min(13, 100 - b0);
  const float* bias = dir ? bias_b : bias_f;
  const float4* wsrc4 = (const float4*)(wt4 + dir * 30000);
  float4* Wlds4 = (float4*)Wlds;
#pragma unroll
  for (int q = 0; q < 8; q++) { int idx = t + 1024 * q; if (idx < 7500) Wlds4[idx] = wsrc4[idx]; }
  int row = w; bool erow = (w < nrows);
  if (erow) {
    hl[row * 112 + lane] = 0.f;
    if (hi) hl[row * 112 + 64 + lane] = 0.f;
  }
  __syncthreads();   // Wlds ready — the ONLY barrier in the kernel
  if (!erow) return;

  int b = b0 + row;
  float nh2 = 0.f, h0 = 0.f, h1 = 0.f;
  float br0 = bias[lane],       br1 = hi ? bias[64 + lane] : 0.f;
  float bh0 = bias[100 + lane], bh1 = hi ? bias[164 + lane] : 0.f;
  float bz0 = bias[200 + lane], bz1 = hi ? bias[264 + lane] : 0.f;
  float nbr2 = wred(br0 * br0 + br1 * br1);
  float nbh2 = wred(bh0 * bh0 + bh1 * bh1);
  float nbz2 = wred(bz0 * bz0 + bz1 * bz1);

  for (int s = 0; s < 20; s++) {
    float mz0, mz1, mr0, mr1;
    mv100x2_reg(Wlds + 2 * 10000, Wlds + 0 * 10000, hl + row * 112, lane, hi,
                mz0, mz1, mr0, mr1);
    int l = dir ? (1999 - (s * 100 + b)) : (s * 100 + b);
    size_t rowg = (size_t)n * 2000 + l;
    size_t iz = (size_t)(dir * 3 + 2) * 32000 + rowg;
    size_t ir = (size_t)(dir * 3 + 0) * 32000 + rowg;
    size_t ih = (size_t)(dir * 3 + 1) * 32000 + rowg;
    const float* uxz = ux + iz * 100;
    const float* uxr = ux + ir * 100;
    const float* uxhp = ux + ih * 100;
    float uz0 = uxz[lane],  uz1 = hi ? uxz[lane + 64] : 0.f;
    float ur0 = uxr[lane],  ur1 = hi ? uxr[lane + 64] : 0.f;
    float uxh0 = uxhp[lane], uxh1 = hi ? uxhp[lane + 64] : 0.f;
    float Cz = nub[iz], ubz = nub[192000 + iz];
    float Cr = nub[ir], ubr = nub[192000 + ir];
    float Ch = nub[ih], ubh = nub[192000 + ih];
    float xnh = sqrt_(fmaxf(nh2, MINF));
    float alphah = artanh_ov(xnh);
    float cz0, cz1, Fz, cr0, cr1, Fr;
    gate_ot(mz0, mz1, uz0, uz1, bz0, bz1, Cz, ubz, nbz2, alphah, cz0, cz1, Fz);
    gate_ot(mr0, mr1, ur0, ur1, br0, br1, Cr, ubr, nbr2, alphah, cr0, cr1, Fr);
    float lgz = artanh_ov(sqrt_(Fz));
    float z0 = sigm_f(lgz * cz0), z1 = sigm_f(lgz * cz1);
    float lgr = artanh_ov(sqrt_(Fr));
    float rg0 = sigm_f(lgr * cr0), rg1 = sigm_f(lgr * cr1);
    float mx0 = rg0 * h0, mx1 = rg1 * h1;
    float G = wred(mx0 * mx0 + mx1 * mx1);
    float mxnr = sqrt_(fmaxf(G, MINF));
    float srh = tanh_f(mxnr * alphah) * rcp_(mxnr);
    rhl[row * 112 + lane] = srh * mx0;
    if (hi) rhl[row * 112 + lane + 64] = srh * mx1;
    float nrh2 = srh * srh * G;
    float mh0, mh1;
    mv100_reg(Wlds + 1 * 10000, rhl + row * 112, lane, hi, mh0, mh1);
    float xnrh = sqrt_(fmaxf(nrh2, MINF));
    float alpharh = artanh_ov(xnrh);
    float ct0, ct1, T;
    gate_ot(mh0, mh1, uxh0, uxh1, bh0, bh1, Ch, ubh, nbh2, alpharh, ct0, ct1, T);
    float U = wred(h0 * ct0 + h1 * ct1);
    float rdd = rcp_(fmaxf(1.f - 2.f * U + nh2 * T, MINF));
    float cAd = (1.f - 2.f * U + T) * rdd, cBd = (1.f - nh2) * rdd;
    float d0 = -cAd * h0 + cBd * ct0, d1 = -cAd * h1 + cBd * ct1;
    float nd2 = fmaxf(cAd * cAd * nh2 - 2.f * cAd * cBd * U + cBd * cBd * T, MINF);
    float zd0 = z0 * d0, zd1 = z1 * d1;
    float P = wred(zd0 * zd0 + zd1 * zd1);
    float Q = wred(h0 * zd0 + h1 * zd1);
    float xnd = sqrt_(nd2);
    float mxnp = sqrt_(fmaxf(P, MINF));
    float sp = tanh_f(mxnp * artanh_ov(xnd)) * rcp_(mxnp);
    float y2p = sp * sp * P, xyp = sp * Q;
    float r3 = rcp_(fmaxf(1.f + 2.f * xyp + nh2 * y2p, MINF));
    float A1 = (1.f + 2.f * xyp + y2p) * r3, B1 = (1.f - nh2) * r3 * sp;
    float hn0 = A1 * h0 + B1 * zd0, hn1 = A1 * h1 + B1 * zd1;
    nh2 = fmaxf(A1 * A1 * nh2 + 2.f * A1 * B1 * Q + B1 * B1 * P, 0.f);
    h0 = hn0; h1 = hn1;
    hl[row * 112 + lane] = hn0;
    if (hi) hl[row * 112 + lane + 64] = hn1;
    float* fd = f + (((size_t)n * 20 + s) * 100 + b) * 200 + dir * 100;
    fd[lane] = hn0;
    if (hi) fd[lane + 64] = hn1;
  }
}

// ---------------- K4ag: Wp-GEMM reduced in-register to per-row scalars ----------------
// mx is never materialized. Outputs per (ch, row): A=|mx_half|^2, B=<mx_half,bp>,
// M=<mx_half,cl>; ch==0 also writes nf2=|f|^2. grid 1000, dyn LDS 77824 B.
__global__ __launch_bounds__(256, 2) void k4ag(const float* __restrict__ f,
                                               const float* __restrict__ wp4,
                                               const float* __restrict__ bp,
                                               const float* __restrict__ cl,
                                               float* __restrict__ Ah, float* __restrict__ Bh,
                                               float* __restrict__ Mh, float* __restrict__ nf2o) {
  extern __shared__ float4 g4[];
  float4* wl = g4;
  float4* pl = g4 + 3200;
  int t = threadIdx.x;
  int bx = blockIdx.x;
  int ch = bx & 1, tile = bx >> 1;
  int row0 = tile * 64;
  int cg = t & 31, rg = t >> 5;
  const float4* wsrc = (const float4*)wp4 + (size_t)ch * 5000;
  const float4* psrc = (const float4*)(f + (size_t)row0 * 200);
  float acc[8][4] = {};
  float nfa[8] = {};
  for (int kc = 0; kc < 2; kc++) {
    __syncthreads();
#pragma unroll
    for (int q = 0; q < 13; q++) {
      int idx = t + 256 * q;
      if (idx < 3200) {
        int k4 = idx >> 7, c = idx & 127;
        float4 v = {0, 0, 0, 0};
        if (c < 100) v = wsrc[(kc * 25 + k4) * 100 + c];
        wl[idx] = v;
      }
    }
#pragma unroll
    for (int q = 0; q < 7; q++) {
      int idx = t + 256 * q;
      if (idx < 1600) {
        int r = idx / 25, k4 = idx % 25;
        pl[r * 26 + k4] = psrc[r * 50 + kc * 25 + k4];
      }
    }
    __syncthreads();
    if (cg < 25) {
#pragma unroll
      for (int i = 0; i < 8; i++) {
        float4 v = pl[(rg * 8 + i) * 26 + cg];
        nfa[i] += v.x * v.x + v.y * v.y + v.z * v.z + v.w * v.w;
      }
    }
#pragma unroll 5
    for (int k4 = 0; k4 < 25; k4++) {
      float4 wv[4];
#pragma unroll
      for (int j = 0; j < 4; j++) wv[j] = wl[k4 * 128 + cg + 32 * j];
#pragma unroll
      for (int i = 0; i < 8; i++) {
        float4 pv = pl[(rg * 8 + i) * 26 + k4];
#pragma unroll
        for (int j = 0; j < 4; j++)
          acc[i][j] += pv.x * wv[j].x + pv.y * wv[j].y + pv.z * wv[j].z + pv.w * wv[j].w;
      }
    }
  }
  float bpc[4], clc[4];
#pragma unroll
  for (int j = 0; j < 4; j++) {
    int lc = cg + 32 * j;
    bool v = lc < 100;
    bpc[j] = v ? bp[ch * 100 + lc] : 0.f;
    clc[j] = v ? cl[ch * 100 + lc] : 0.f;
  }
#pragma unroll
  for (int i = 0; i < 8; i++) {
    int r = row0 + rg * 8 + i;
    float a2 = acc[i][0] * acc[i][0] + acc[i][1] * acc[i][1] +
               acc[i][2] * acc[i][2] + acc[i][3] * acc[i][3];
    float ab = acc[i][0] * bpc[0] + acc[i][1] * bpc[1] +
               acc[i][2] * bpc[2] + acc[i][3] * bpc[3];
    float ac = acc[i][0] * clc[0] + acc[i][1] * clc[1] +
               acc[i][2] * clc[2] + acc[i][3] * clc[3];
    float nf = nfa[i];
#pragma unroll
    for (int m = 16; m > 0; m >>= 1) {
      a2 += __shfl_xor(a2, m, 64);
      ab += __shfl_xor(ab, m, 64);
      ac += __shfl_xor(ac, m, 64);
      nf += __shfl_xor(nf, m, 64);
    }
    if (cg == 0) {
      Ah[ch * 32000 + r] = a2;
      Bh[ch * 32000 + r] = ab;
      Mh[ch * 32000 + r] = ac;
      if (ch == 0) nf2o[r] = nf;
    }
  }
}

// ---------------- K4ael: scalar epilogue — lorentz logits a, gamma ----------------
// grid 125 x 256 = 32000 threads, one row each.
__global__ __launch_bounds__(256) void k4ael(const float* __restrict__ Ah,
                                             const float* __restrict__ Bh,
                                             const float* __restrict__ Mh,
                                             const float* __restrict__ nf2a,
                                             const float* __restrict__ cl,
                                             const float* __restrict__ beta_p,
                                             float* __restrict__ a_out,
                                             float* __restrict__ g_out) {
  int r = blockIdx.x * 256 + threadIdx.x;
  float A = Ah[r] + Ah[32000 + r];
  float B = Bh[r] + Bh[32000 + r];
  float Mc = Mh[r] + Mh[32000 + r];
  float nf2 = nf2a[r];
  float c200 = cl[200], nbp2 = cl[204], bpcl = cl[205];
  float beta = beta_p[0];
  float alx = artanh_ov(sqrt_(fmaxf(nf2, MINF)));
  float mxn = sqrt_(fmaxf(A, MINF));
  float gam = tanh_f(mxn * alx) * rcp_(mxn);
  float x2 = gam * gam * A, xy = gam * B;
  float rd = rcp_(fmaxf(1.f + 2.f * xy + x2 * nbp2, MINF));
  float cA = (1.f + 2.f * xy + nbp2) * gam * rd, cB = (1.f - x2) * rd;
  float r2 = fmaxf(cA * cA * A + 2.f * cA * cB * B + cB * cB * nbp2, 0.f);
  float dc = cA * Mc + cB * bpcl;
  float pm = (-2.f * dc + (1.f + r2) * c200) / (1.f - r2 + EPSF);
  pm = fminf(fmaxf(pm, 1.f + EPSF), 1e16f);
  float av = -beta * arcosh_(pm) - 1.f;
  float invg = 1.f - 4.f * nf2 / ((1.f + nf2) * (1.f + nf2));
  invg = fminf(fmaxf(invg, EPSF), 1.f - EPSF);
  float gv = fminf(fmaxf(rsq_(invg), 1.f + EPSF), 1e16f);
  a_out[r] = av;
  g_out[r] = gv;
}

// ---------------- K4b: per-sample softmax weights ----------------
__global__ __launch_bounds__(256) void k4b(const float* __restrict__ a_in,
                                           const float* __restrict__ g_in,
                                           float* __restrict__ wgt) {
  __shared__ float rl[2000];
  __shared__ float sred[4];
  __shared__ float rsinv[100];
  int n = blockIdx.x; int t = threadIdx.x;
  int w = t >> 6, lane = t & 63;
  const float* ap = a_in + n * 2000;
  const float* gp = g_in + n * 2000;
  float av[8]; float am = -1e30f;
#pragma unroll
  for (int q = 0; q < 8; q++) {
    int i = t + 256 * q;
    av[q] = (i < 2000) ? ap[i] : -1e30f;
    am = fmaxf(am, av[q]);
  }
  am = wredmax(am);
  if (lane == 0) sred[w] = am;
  __syncthreads();
  float amax = fmaxf(fmaxf(sred[0], sred[1]), fmaxf(sred[2], sred[3]));
#pragma unroll
  for (int q = 0; q < 8; q++) {
    int i = t + 256 * q;
    if (i < 2000) rl[i] = expf(av[q] - amax) * gp[i];
  }
  __syncthreads();
  if (t < 100) {
    float ssum = 0.f;
#pragma unroll
    for (int s = 0; s < 20; s++) ssum += rl[s * 100 + t];
    rsinv[t] = 1.f / ssum;
  }
  __syncthreads();
#pragma unroll
  for (int q = 0; q < 8; q++) {
    int i = t + 256 * q;
    if (i < 2000) wgt[n * 2000 + i] = rl[i] * rsinv[i % 100];
  }
}

// ---------------- K4c: klein aggregation + final GEMM W2 ----------------
__global__ __launch_bounds__(256) void k4c(const float* __restrict__ f, const float* __restrict__ wgt,
                                           const float* __restrict__ W2, const float* __restrict__ b2,
                                           float* __restrict__ out) {
  __shared__ float cw[100];
  __shared__ float part[4][204];
  __shared__ float ol[200];
  __shared__ float sred[4];
  int bx = blockIdx.x; int n = bx / 20, s = bx % 20;
  int t = threadIdx.x; int w = t >> 6; int lane = t & 63;
  const float* fb = f + ((size_t)n * 20 + s) * 100 * 200;
  for (int bi = w * 25; bi < w * 25 + 25; bi++) {
    const float* fr = fb + bi * 200;
    float v0 = fr[lane], v1 = fr[lane + 64], v2 = fr[lane + 128];
    float v3 = (lane < 8) ? fr[lane + 192] : 0.f;
    float s2 = wred(v0 * v0 + v1 * v1 + v2 * v2 + v3 * v3);
    if (lane == 0) cw[bi] = wgt[n * 2000 + s * 100 + bi] * 2.f * rcp_(1.f + s2);
  }
  __syncthreads();
  float o0 = 0, o1 = 0, o2 = 0, o3 = 0;
  for (int bi = w * 25; bi < w * 25 + 25; bi++) {
    float c = cw[bi];
    const float* fr = fb + bi * 200;
    o0 += c * fr[lane]; o1 += c * fr[lane + 64]; o2 += c * fr[lane + 128];
    if (lane < 8) o3 += c * fr[lane + 192];
  }
  part[w][lane] = o0; part[w][lane + 64] = o1; part[w][lane + 128] = o2;
  if (lane < 8) part[w][lane + 192] = o3;
  __syncthreads();
  float o = 0.f;
  if (t < 200) o = part[0][t] + part[1][t] + part[2][t] + part[3][t];
  float ps = (t < 200) ? o * o : 0.f;
  ps = wred(ps);
  if (lane == 0) sred[w] = ps;
  __syncthreads();
  float no2 = sred[0] + sred[1] + sred[2] + sred[3];
  float denom = 1.f + sqrtf(1.f + no2);
  if (t < 200) ol[t] = o / denom;
  __syncthreads();
  const float4* ol4 = (const float4*)ol;
#pragma unroll
  for (int jj = 0; jj < 3; jj++) {
    int j = t + 256 * jj;
    const float4* wrow = (const float4*)(W2 + (size_t)j * 200);
    float a0 = 0, a1 = 0, a2 = 0, a3 = 0;
    for (int k4 = 0; k4 < 50; k4++) {
      float4 wv = wrow[k4]; float4 ov = ol4[k4];
      a0 += wv.x * ov.x; a1 += wv.y * ov.y; a2 += wv.z * ov.z; a3 += wv.w * ov.w;
    }
    out[((size_t)n * 20 + s) * 768 + j] = a0 + a1 + a2 + a3 + b2[j];
  }
}

extern "C" void kernel_launch(void* const* d_in, const int* in_sizes, int n_in,
                              void* d_out, int out_size, void* d_ws, size_t ws_size,
                              hipStream_t stream) {
  const float* x_     = (const float*)d_in[0];
  const float* W1     = (const float*)d_in[1];
  const float* b1     = (const float*)d_in[2];
  const float* W2     = (const float*)d_in[3];
  const float* b2     = (const float*)d_in[4];
  const float* Wih_f  = (const float*)d_in[5];
  const float* Whh_f  = (const float*)d_in[6];
  const float* bias_f = (const float*)d_in[7];
  const float* Wih_b  = (const float*)d_in[8];
  const float* Whh_b  = (const float*)d_in[9];
  const float* bias_b = (const float*)d_in[10];
  const float* centroid = (const float*)d_in[11];
  const float* Wp     = (const float*)d_in[12];
  const float* bp     = (const float*)d_in[13];
  const float* beta   = (const float*)d_in[14];
  float* out = (float*)d_out;
  float* ws = (float*)d_ws;
  float* p   = ws + OFF_P;
  float* ux  = ws + OFF_UX;
  float* wt4 = ws + OFF_WT4;
  float* f   = ws + OFF_F;
  float* wi4 = ws + OFF_WI4;
  float* w1p = ws + OFF_W1P;
  float* wp4 = ws + OFF_WP4;
  float* cl  = ws + OFF_CL;
  float* aa  = ws + OFF_A;
  float* gg  = ws + OFF_G;
  float* wg  = ws + OFF_WGT;
  // k4 row-scalar partials in the (dead-after-k3) ux region:
  float* Ah  = ws + OFF_UX;            // 2*32000
  float* Bh  = ws + OFF_UX + 64000;    // 2*32000
  float* Mh  = ws + OFF_UX + 128000;   // 2*32000
  float* nf2 = ws + OFF_UX + 192000;   // 32000
  // nub: fused into k2 if ws has room for the tail region (must coexist with p);
  // else fallback to the separate k2b pass with nub overwriting dead p.
  bool fuse_nub = ws_size >= (size_t)(OFF_NUBT + 384000u) * 4u;
  float* nub = fuse_nub ? (ws + OFF_NUBT) : (ws + OFF_P);

  (void)hipFuncSetAttribute(reinterpret_cast<const void*>(k3),
                            hipFuncAttributeMaxDynamicSharedMemorySize, K3_LDS_BYTES);
  (void)hipFuncSetAttribute(reinterpret_cast<const void*>(k2t<true>),
                            hipFuncAttributeMaxDynamicSharedMemorySize, K2_LDS_BYTES);
  (void)hipFuncSetAttribute(reinterpret_cast<const void*>(k2t<false>),
                            hipFuncAttributeMaxDynamicSharedMemorySize, K2_LDS_BYTES);
  (void)hipFuncSetAttribute(reinterpret_cast<const void*>(k4ag),
                            hipFuncAttributeMaxDynamicSharedMemorySize, K4G_LDS_BYTES);

  k0_pack<<<926, 256, 0, stream>>>(Whh_f, Whh_b, Wih_f, Wih_b, W1, Wp, centroid, bp,
                                   wt4, wi4, w1p, wp4, cl);
  k1<<<500, 256, 0, stream>>>(x_, w1p, b1, p);
  if (fuse_nub) {
    k2t<true><<<3000, 256, K2_LDS_BYTES, stream>>>(p, wi4, bias_f, bias_b, ux, nub);
  } else {
    k2t<false><<<3000, 256, K2_LDS_BYTES, stream>>>(p, wi4, bias_f, bias_b, ux, nullptr);
    k2b<<<3000, 256, 0, stream>>>(ux, bias_f, bias_b, nub);
  }
  k3<<<256, 1024, K3_LDS_BYTES, stream>>>(ux, nub, wt4, bias_f, bias_b, f);
  k4ag<<<1000, 256, K4G_LDS_BYTES, stream>>>(f, wp4, bp, cl, Ah, Bh, Mh, nf2);
  k4ael<<<125, 256, 0, stream>>>(Ah, Bh, Mh, nf2, cl, beta, aa, gg);
  k4b<<<16, 256, 0, stream>>>(aa, gg, wg);
  k4c<<<320, 256, 0, stream>>>(f, wg, W2, b2, out);
}